// Round 15
// baseline (457.494 us; speedup 1.0000x reference)
//
#include <hip/hip_runtime.h>
#include <hip/hip_fp16.h>

#define B_ 64
#define L_ 128
#define E_ 300
#define HD_ 200
#define H_ 400
#define S_ 50
#define START_ 48
#define END_ 49
#define NG_ 1600
#define BL_ 8192

// ---- ws layout (bytes) ----
#define OFF_XG   0ull                          // bf16 [8192][1600]  26,214,400
#define OFF_LSTM 26214400ull                   // bf16 [8192][400]  6,553,600 (lstm16; overlays A'/B')
#define OFF_ABF  OFF_LSTM                      // bf16 [8192][320]    5,242,880 (prep->xg)
#define OFF_BBF  (OFF_LSTM + 5242880ull)       // bf16 [1664][320]    1,064,960 (prep->xg)
#define OFF_SH   (OFF_LSTM + 13107200ull)      // max(w8 320,000 ; feats 1,638,400)
#define OFF_INV  (OFF_SH + 1638400ull)         // f32 [1600]  6,400
#define OFF_WTB  (OFF_INV + 6400ull)           // bf16 [64][400] 51,200 (wtagB)
#define OFF_BIA  (OFF_WTB + 80000ull)          // f32 [1600]  6,400
#define OFF_PART (OFF_BIA + 6400ull)           // f32 [64] per-batch partials

#define NA_T 2621440   // 8192*320
#define NB_T 532480    // 1664*320
// prep items = NA_T + NB_T + 25600 (wtagB) + 1600 (biasC) = 3,181,120
// grid 12427*256 = 3,181,312 >= 3,181,120  (R10 lesson: verify!)
#define PREP_BLOCKS 12427

typedef __attribute__((ext_vector_type(8))) short short8;
typedef __attribute__((ext_vector_type(4))) float f32x4;

__device__ __forceinline__ unsigned short f32_to_bf16(float f) {
    unsigned u = __float_as_uint(f);
    unsigned r = u + 0x7fffu + ((u >> 16) & 1u);
    return (unsigned short)(r >> 16);
}
__device__ __forceinline__ float bf16_to_f32(unsigned short s) {
    return __uint_as_float(((unsigned)s) << 16);
}
// 4-wide int8 dot with i32 accumulate: v_dot4_i32_i8 (fallback: manual sext).
__device__ __forceinline__ int dot4(unsigned a, unsigned b, int c) {
#if __has_builtin(__builtin_amdgcn_sdot4)
    return __builtin_amdgcn_sdot4(a, b, c, false);
#else
    c += (int)(signed char)(a)       * (int)(signed char)(b);
    c += (int)(signed char)(a >> 8)  * (int)(signed char)(b >> 8);
    c += (int)(signed char)(a >> 16) * (int)(signed char)(b >> 16);
    c += (int)(signed char)(a >> 24) * (int)(signed char)(b >> 24);
    return c;
#endif
}

// ---------------- prep: A' gather->bf16(pad 320), B' weights->bf16, wtagB bf16[64][400], biasC.
__global__ void prep_kernel(const int* __restrict__ words, const float* __restrict__ emb,
                            const float* __restrict__ wihf, const float* __restrict__ wihb,
                            const float* __restrict__ bfc, const float* __restrict__ bbc,
                            const float* __restrict__ wtag,
                            unsigned short* __restrict__ Abf, unsigned short* __restrict__ Bbf,
                            unsigned short* __restrict__ wtagB, float* __restrict__ biasC) {
    long g = (long)blockIdx.x * 256 + threadIdx.x;
    if (g < NA_T) {
        int i = (int)(g / 320), k = (int)(g % 320);
        float v = (k < E_) ? emb[(long)words[i] * E_ + k] : 0.f;
        Abf[g] = f32_to_bf16(v);
        return;
    }
    g -= NA_T;
    if (g < NB_T) {
        int r = (int)(g / 320), k = (int)(g % 320);
        float v = 0.f;
        if (r < NG_ && k < E_) v = (r < 800) ? wihf[r * E_ + k] : wihb[(r - 800) * E_ + k];
        Bbf[g] = f32_to_bf16(v);
        return;
    }
    g -= NB_T;
    if (g < 25600) {   // wtagB [64][400], rows >=50 zero
        int s = (int)(g / 400), k = (int)(g % 400);
        float v = (s < S_) ? wtag[s * H_ + k] : 0.f;
        wtagB[g] = f32_to_bf16(v);
        return;
    }
    g -= 25600;
    if (g < 1600) { biasC[g] = (g < 800) ? bfc[g] : bbc[g - 800]; return; }
}

// ---------------- w_hh quant: one WAVE per row. Global w8 layout (k-major chunks):
//   [dir] { chunks [j=0..11][row 0..799] uint4 (k=16j..16j+15) at (j*800+row)*16,
//           tails  [row] uint2 (k=192..199) at 153600 + row*8 }   (160,000 B per dir)
__global__ __launch_bounds__(256) void quant_kernel(const float* __restrict__ whh_f,
                                                    const float* __restrict__ whh_b,
                                                    signed char* __restrict__ w8,
                                                    float* __restrict__ invs) {
    int gw = (int)((blockIdx.x * 256 + threadIdx.x) >> 6);
    int lane = threadIdx.x & 63;
    if (gw >= 1600) return;
    int dir = gw / 800, row = gw % 800;
    const float* w = (dir ? whh_b : whh_f) + row * HD_;
    float m = 1e-20f;
    for (int k = lane; k < HD_; k += 64) m = fmaxf(m, fabsf(w[k]));
    for (int off = 32; off; off >>= 1) m = fmaxf(m, __shfl_xor(m, off));
    float s = 127.f / m;
    if (lane < 50) {
        int k0 = lane * 4;
        unsigned pk = 0;
#pragma unroll
        for (int i = 0; i < 4; ++i) {
            int v = (int)rintf(w[k0 + i] * s);
            pk |= ((unsigned)(v & 0xff)) << (8 * i);
        }
        unsigned char* base = (unsigned char*)w8 + dir * 160000;
        if (lane < 48) {
            int j = lane >> 2, wsel = lane & 3;
            *(unsigned*)(base + (size_t)(j * 800 + row) * 16 + wsel * 4) = pk;
        } else {
            *(unsigned*)(base + 153600 + (size_t)row * 8 + (lane - 48) * 4) = pk;
        }
    }
    if (lane == 0) invs[gw] = m / 16129.f;   // m/(127*127)
}

// ---------------- xg GEMM (MFMA bf16), staged from pre-converted bf16 A'/B'. (unchanged)
__global__ __launch_bounds__(256) void xg_gemm(const unsigned short* __restrict__ Abf,
                                               const unsigned short* __restrict__ Bbf,
                                               const float* __restrict__ biasC,
                                               unsigned short* __restrict__ xg) {
    __shared__ unsigned short As[128 * 40];
    __shared__ unsigned short Bs[128 * 40];
    int tid = threadIdx.x;
    int bm = blockIdx.y * 128;
    int bn = blockIdx.x * 128;
    int srow = tid >> 1, half = tid & 1;
    int lane = tid & 63, wave = tid >> 6, r16 = lane & 15, kh = lane >> 4;

    f32x4 acc[2][8];
#pragma unroll
    for (int mi = 0; mi < 2; ++mi)
#pragma unroll
        for (int ni = 0; ni < 8; ++ni) acc[mi][ni] = (f32x4){0.f, 0.f, 0.f, 0.f};

    const unsigned short* Ar = Abf + (long)(bm + srow) * 320;
    const unsigned short* Br = Bbf + (long)(bn + srow) * 320;

    for (int k0 = 0; k0 < 320; k0 += 32) {
#pragma unroll
        for (int j = 0; j < 2; ++j) {
            int off = half * 16 + j * 8;
            *(uint4*)&As[srow * 40 + off] = *(const uint4*)(Ar + k0 + off);
            *(uint4*)&Bs[srow * 40 + off] = *(const uint4*)(Br + k0 + off);
        }
        __syncthreads();
        short8 af[2], bfv[8];
#pragma unroll
        for (int mi = 0; mi < 2; ++mi)
            af[mi] = *(const short8*)&As[(wave * 32 + mi * 16 + r16) * 40 + kh * 8];
#pragma unroll
        for (int ni = 0; ni < 8; ++ni)
            bfv[ni] = *(const short8*)&Bs[(ni * 16 + r16) * 40 + kh * 8];
#pragma unroll
        for (int mi = 0; mi < 2; ++mi)
#pragma unroll
            for (int ni = 0; ni < 8; ++ni)
                acc[mi][ni] = __builtin_amdgcn_mfma_f32_16x16x32_bf16(af[mi], bfv[ni], acc[mi][ni], 0, 0, 0);
        __syncthreads();
    }
#pragma unroll
    for (int ni = 0; ni < 8; ++ni) {
        int g = bn + ni * 16 + r16;
        if (g < NG_) {
            float bias = biasC[g];
#pragma unroll
            for (int mi = 0; mi < 2; ++mi) {
#pragma unroll
                for (int r = 0; r < 4; ++r) {
                    int row = bm + wave * 32 + mi * 16 + kh * 4 + r;
                    xg[(long)row * NG_ + g] = f32_to_bf16(acc[mi][ni][r] + bias);
                }
            }
        }
    }
}

// ---------------- LSTM recurrence: explicit two-pipe split (R13 insight: h-LDS and
// w-VMEM overlap; R13's 2670cyc/step = stream 160KB. Now stream only chunks 0..7
// (102.4KB/step, ~1710cyc) and keep chunks 8..11+tail LDS-resident (57.6KB; LDS pipe
// has ~1250cyc of h-broadcast + ~550cyc of these reads) -> balanced ~1800cyc/step).
// 512 thr, 2 rows/thread {tid, tid+400} (h-reads shared across the pair); demand ~58
// VGPR < the 64 cap this shape gets (R13) -> no spill. lstm_out now bf16.
__global__ __launch_bounds__(512) void lstm_rec(const unsigned short* __restrict__ xg,
                                                const signed char* __restrict__ w8,
                                                const float* __restrict__ invs,
                                                unsigned short* __restrict__ lstm16) {
    __shared__ __align__(16) uint4 wl4[3200];           // chunks 8..11: [jj][row] 51,200 B
    __shared__ __align__(16) uint2 wt2[800];            // tails: 6,400 B
    __shared__ __align__(16) unsigned char hbuf[256];   // int8 h (200 used)
    __shared__ float a_lds[800];                        // gate activations
    int tid = threadIdx.x;
    int dir = blockIdx.x >> 6;
    int b = blockIdx.x & 63;
    bool act = tid < 400;
    int tw = act ? tid : 0;

    const unsigned char* wbase = (const unsigned char*)w8 + dir * 160000;
    {   // stage LDS-resident part: chunks 8..11 + tails
        const uint4* src = (const uint4*)(wbase + (size_t)8 * 800 * 16);
        for (int i = tid; i < 3200; i += 512) wl4[i] = src[i];
        const uint2* st = (const uint2*)(wbase + 153600);
        for (int i = tid; i < 800; i += 512) wt2[i] = st[i];
    }
    float invA = act ? invs[dir * 800 + tid] : 0.f;
    float invB = act ? invs[dir * 800 + tid + 400] : 0.f;
    if (tid < 64) ((unsigned*)hbuf)[tid] = 0u;
    float c = 0.f;
    __syncthreads();

    const uint4* h4c = (const uint4*)hbuf;
    const uint2* ht2 = (const uint2*)(hbuf + 192);
    const unsigned short* xbase = xg + (long)b * L_ * NG_ + dir * 800;

    int t0 = dir ? (L_ - 1) : 0;
    float xa = act ? bf16_to_f32(xbase[(long)t0 * NG_ + tid]) : 0.f;
    float xb = act ? bf16_to_f32(xbase[(long)t0 * NG_ + tid + 400]) : 0.f;

    for (int step = 0; step < L_; ++step) {
        int t = dir ? (L_ - 1 - step) : step;
        float xa_n = 0.f, xb_n = 0.f;
        if (act && step + 1 < L_) {
            int tn = dir ? (t - 1) : (t + 1);
            xa_n = bf16_to_f32(xbase[(long)tn * NG_ + tid]);
            xb_n = bf16_to_f32(xbase[(long)tn * NG_ + tid + 400]);
        }
        if (act) {
            int di0 = 0, di1 = 0;
#pragma unroll
            for (int j = 0; j < 8; ++j) {   // streamed chunks (VMEM/L2 pipe)
                uint4 wA = *(const uint4*)(wbase + (size_t)(j * 800 + tw) * 16);
                uint4 wB = *(const uint4*)(wbase + (size_t)(j * 800 + tw + 400) * 16);
                uint4 hh = h4c[j];
                di0 = dot4(wA.x, hh.x, di0); di0 = dot4(wA.y, hh.y, di0);
                di0 = dot4(wA.z, hh.z, di0); di0 = dot4(wA.w, hh.w, di0);
                di1 = dot4(wB.x, hh.x, di1); di1 = dot4(wB.y, hh.y, di1);
                di1 = dot4(wB.z, hh.z, di1); di1 = dot4(wB.w, hh.w, di1);
            }
#pragma unroll
            for (int jj = 0; jj < 4; ++jj) {   // LDS-resident chunks 8..11
                uint4 wA = wl4[jj * 800 + tw];
                uint4 wB = wl4[jj * 800 + tw + 400];
                uint4 hh = h4c[8 + jj];
                di0 = dot4(wA.x, hh.x, di0); di0 = dot4(wA.y, hh.y, di0);
                di0 = dot4(wA.z, hh.z, di0); di0 = dot4(wA.w, hh.w, di0);
                di1 = dot4(wB.x, hh.x, di1); di1 = dot4(wB.y, hh.y, di1);
                di1 = dot4(wB.z, hh.z, di1); di1 = dot4(wB.w, hh.w, di1);
            }
            {   // tails k=192..199
                uint2 wA = wt2[tw];
                uint2 wB = wt2[tw + 400];
                uint2 hh = ht2[0];
                di0 = dot4(wA.x, hh.x, di0); di0 = dot4(wA.y, hh.y, di0);
                di1 = dot4(wB.x, hh.x, di1); di1 = dot4(wB.y, hh.y, di1);
            }
            float pa = xa + (float)di0 * invA;   // i (tid<200) / f
            float pb = xb + (float)di1 * invB;   // g (tid<200) / o
            a_lds[tid] = 1.f / (1.f + __expf(-pa));
            if (tid < 200) {
                float e = __expf(-2.f * pb);                     // tanh(g)
                a_lds[400 + tid] = 2.f / (1.f + e) - 1.f;
            } else {
                a_lds[400 + tid] = 1.f / (1.f + __expf(-pb));    // sig(o)
            }
        }
        __syncthreads();
        if (tid < HD_) {
            float ig = a_lds[tid];
            float fg = a_lds[200 + tid];
            float gg = a_lds[400 + tid];
            float og = a_lds[600 + tid];
            c = fg * c + ig * gg;
            float ec = __expf(-2.f * c);
            float hn = og * (2.f / (1.f + ec) - 1.f);
            ((signed char*)hbuf)[tid] = (signed char)(int)rintf(hn * 127.f);
            lstm16[((long)(b * L_ + t)) * H_ + dir * HD_ + tid] = f32_to_bf16(hn);
        }
        xa = xa_n; xb = xb_n;
        __syncthreads();
    }
}

// ---------------- features via MFMA: feats[8192][50] = lstm16[8192][400] @ wtagB^T + btag.
// Tile M=128 x N=64 (50 used), K=400 (13 k-iters, zero-padded last). 64 blocks.
__global__ __launch_bounds__(256) void feat_kernel(const unsigned short* __restrict__ lstm16,
                                                   const unsigned short* __restrict__ wtagB,
                                                   const float* __restrict__ btag,
                                                   float* __restrict__ feats) {
    __shared__ unsigned short As[128 * 40];
    __shared__ unsigned short Bs[64 * 40];
    int tid = threadIdx.x;
    int bm = blockIdx.x * 128;
    int srow = tid >> 1, half = tid & 1;
    int lane = tid & 63, wave = tid >> 6, r16 = lane & 15, kh = lane >> 4;

    f32x4 acc[2][4];
#pragma unroll
    for (int mi = 0; mi < 2; ++mi)
#pragma unroll
        for (int ni = 0; ni < 4; ++ni) acc[mi][ni] = (f32x4){0.f, 0.f, 0.f, 0.f};

    const unsigned short* Ar = lstm16 + (long)(bm + srow) * 400;
    const unsigned short* Br = wtagB + (long)srow * 400;

    for (int k0 = 0; k0 < 400; k0 += 32) {
#pragma unroll
        for (int j = 0; j < 2; ++j) {
            int off = half * 16 + j * 8;
            bool kv = (k0 + off + 8 <= 400);
            uint4 z = make_uint4(0u, 0u, 0u, 0u);
            *(uint4*)&As[srow * 40 + off] = kv ? *(const uint4*)(Ar + k0 + off) : z;
            if (srow < 64)
                *(uint4*)&Bs[srow * 40 + off] = kv ? *(const uint4*)(Br + k0 + off) : z;
        }
        __syncthreads();
        short8 af[2], bfv[4];
#pragma unroll
        for (int mi = 0; mi < 2; ++mi)
            af[mi] = *(const short8*)&As[(wave * 32 + mi * 16 + r16) * 40 + kh * 8];
#pragma unroll
        for (int ni = 0; ni < 4; ++ni)
            bfv[ni] = *(const short8*)&Bs[(ni * 16 + r16) * 40 + kh * 8];
#pragma unroll
        for (int mi = 0; mi < 2; ++mi)
#pragma unroll
            for (int ni = 0; ni < 4; ++ni)
                acc[mi][ni] = __builtin_amdgcn_mfma_f32_16x16x32_bf16(af[mi], bfv[ni], acc[mi][ni], 0, 0, 0);
        __syncthreads();
    }
#pragma unroll
    for (int ni = 0; ni < 4; ++ni) {
        int g = ni * 16 + r16;
        if (g < S_) {
            float bias = btag[g];
#pragma unroll
            for (int mi = 0; mi < 2; ++mi) {
#pragma unroll
                for (int r = 0; r < 4; ++r) {
                    int row = bm + wave * 32 + mi * 16 + kh * 4 + r;
                    feats[(long)row * S_ + g] = acc[mi][ni][r] + bias;
                }
            }
        }
    }
}

// ---------------- CRF forward + labeled score (per-batch partials, no atomics)
__global__ __launch_bounds__(512) void crf_kernel(const float* __restrict__ feats,
                                                  const float* __restrict__ trans,
                                                  const int* __restrict__ tags,
                                                  const int* __restrict__ seqlens,
                                                  float* __restrict__ part) {
    __shared__ float Tt[S_ * S_];   // Tt[j*50+i] = trans[i*50+j]
    __shared__ float alpha[S_];
    __shared__ float lastal[S_];
    __shared__ int tg[L_];
    int tid = threadIdx.x;
    int b = blockIdx.x;
    for (int idx = tid; idx < S_ * S_; idx += 512) {
        int j = idx / S_, i = idx % S_;
        Tt[idx] = trans[i * S_ + j];
    }
    if (tid < L_) tg[tid] = tags[b * L_ + tid];
    int slen = seqlens[b];
    const float* fb = feats + (long)b * L_ * S_;
    __syncthreads();
    if (tid < S_) {
        float a = Tt[tid * S_ + START_] + fb[tid];
        alpha[tid] = a;
        if (slen == 1) lastal[tid] = a;
    }
    __syncthreads();
    int j = tid >> 3, sub = tid & 7;
    bool jact = j < S_;
    for (int t = 1; t < L_; ++t) {
        float anew = 0.f;
        if (jact) {
            float m = -1e30f;
            for (int i = sub; i < S_; i += 8) m = fmaxf(m, alpha[i] + Tt[j * S_ + i]);
            m = fmaxf(m, __shfl_xor(m, 1));
            m = fmaxf(m, __shfl_xor(m, 2));
            m = fmaxf(m, __shfl_xor(m, 4));
            float s = 0.f;
            for (int i = sub; i < S_; i += 8) s += __expf(alpha[i] + Tt[j * S_ + i] - m);
            s += __shfl_xor(s, 1);
            s += __shfl_xor(s, 2);
            s += __shfl_xor(s, 4);
            anew = m + __logf(s) + fb[t * S_ + j];
        }
        __syncthreads();
        if (jact && sub == 0) {
            alpha[j] = anew;
            if (t == slen - 1) lastal[j] = anew;
        }
        __syncthreads();
    }
    if (tid < 64) {
        float la = (tid < S_) ? (lastal[tid] + Tt[END_ * S_ + tid]) : -1e30f;
        float m = la;
        for (int off = 32; off; off >>= 1) m = fmaxf(m, __shfl_xor(m, off));
        float e = (tid < S_) ? __expf(la - m) : 0.f;
        for (int off = 32; off; off >>= 1) e += __shfl_xor(e, off);
        float unl = m + __logf(e);
        float lab = 0.f;
        for (int tt = tid; tt < L_; tt += 64) {
            if (tt == 0) {
                lab += Tt[tg[0] * S_ + START_] + fb[tg[0]];
            } else if (tt < slen) {
                lab += Tt[tg[tt] * S_ + tg[tt - 1]] + fb[tt * S_ + tg[tt]];
            }
        }
        if (tid == 0) lab += Tt[END_ * S_ + tg[slen - 1]];
        for (int off = 32; off; off >>= 1) lab += __shfl_xor(lab, off);
        if (tid == 0) part[b] = unl - lab;
    }
}

// ---------------- final: deterministic fixed-order sum of 64 partials
__global__ void fin_kernel(const float* __restrict__ part, float* __restrict__ out) {
    float s = 0.f;
    for (int i = 0; i < B_; ++i) s += part[i];
    out[0] = s;
}

extern "C" void kernel_launch(void* const* d_in, const int* in_sizes, int n_in,
                              void* d_out, int out_size, void* d_ws, size_t ws_size,
                              hipStream_t stream) {
    const int*   words = (const int*)d_in[0];
    const int*   slens = (const int*)d_in[1];
    // d_in[2] = masks: semantically (t < seq_len); not read.
    const int*   tags  = (const int*)d_in[3];
    const float* emb   = (const float*)d_in[4];
    const float* wihf  = (const float*)d_in[5];
    const float* whhf  = (const float*)d_in[6];
    const float* bf    = (const float*)d_in[7];
    const float* wihb  = (const float*)d_in[8];
    const float* whhb  = (const float*)d_in[9];
    const float* bb    = (const float*)d_in[10];
    const float* wtag  = (const float*)d_in[11];
    const float* btag  = (const float*)d_in[12];
    const float* trans = (const float*)d_in[13];

    char* ws = (char*)d_ws;
    unsigned short* xg     = (unsigned short*)(ws + OFF_XG);
    unsigned short* lstm16 = (unsigned short*)(ws + OFF_LSTM);
    unsigned short* Abf    = (unsigned short*)(ws + OFF_ABF);  // prep -> xg (overlaid by lstm16)
    unsigned short* Bbf    = (unsigned short*)(ws + OFF_BBF);  // prep -> xg (overlaid by lstm16)
    signed char*    w8     = (signed char*)(ws + OFF_SH);      // quant -> lstm
    float*          fts    = (float*)(ws + OFF_SH);            // feat -> crf (time-shared with w8)
    float*          invs   = (float*)(ws + OFF_INV);
    unsigned short* wtagB  = (unsigned short*)(ws + OFF_WTB);
    float*          biaC   = (float*)(ws + OFF_BIA);
    float*          part   = (float*)(ws + OFF_PART);
    float*          out    = (float*)d_out;

    prep_kernel<<<PREP_BLOCKS, 256, 0, stream>>>(words, emb, wihf, wihb, bf, bb,
                                                 wtag, Abf, Bbf, wtagB, biaC);
    quant_kernel<<<400, 256, 0, stream>>>(whhf, whhb, w8, invs);
    xg_gemm<<<dim3(13, 64), 256, 0, stream>>>(Abf, Bbf, biaC, xg);
    lstm_rec<<<128, 512, 0, stream>>>(xg, w8, invs, lstm16);
    feat_kernel<<<64, 256, 0, stream>>>(lstm16, wtagB, btag, fts);
    crf_kernel<<<64, 512, 0, stream>>>(fts, trans, tags, slens, part);
    fin_kernel<<<1, 1, 0, stream>>>(part, out);
}

// Round 16
// 362.188 us; speedup vs baseline: 1.2631x; 1.2631x over previous
//
#include <hip/hip_runtime.h>
#include <hip/hip_fp16.h>

#define B_ 64
#define L_ 128
#define E_ 300
#define HD_ 200
#define H_ 400
#define S_ 50
#define START_ 48
#define END_ 49
#define NG_ 1600
#define BL_ 8192

// ---- ws layout (bytes) ----
#define OFF_XG   0ull                          // bf16 [8192][1600]  26,214,400
#define OFF_LSTM 26214400ull                   // bf16 [8192][400]  6,553,600 (lstm16; overlays A'/B')
#define OFF_ABF  OFF_LSTM                      // bf16 [8192][320]    5,242,880 (prep->xg)
#define OFF_BBF  (OFF_LSTM + 5242880ull)       // bf16 [1664][320]    1,064,960 (prep->xg)
#define OFF_SH   (OFF_LSTM + 13107200ull)      // max(w8 320,000 ; feats 1,638,400)
#define OFF_INV  (OFF_SH + 1638400ull)         // f32 [1600]  6,400
#define OFF_WTB  (OFF_INV + 6400ull)           // bf16 [64][400] 51,200 (wtagB)
#define OFF_BIA  (OFF_WTB + 80000ull)          // f32 [1600]  6,400
#define OFF_PART (OFF_BIA + 6400ull)           // f32 [64] per-batch partials

#define NA_T 2621440   // 8192*320
#define NB_T 532480    // 1664*320
// prep items = NA_T + NB_T + 25600 (wtagB) + 1600 (biasC) = 3,181,120
// grid 12427*256 = 3,181,312 >= 3,181,120
#define PREP_BLOCKS 12427

typedef __attribute__((ext_vector_type(8))) short short8;
typedef __attribute__((ext_vector_type(4))) float f32x4;

__device__ __forceinline__ unsigned short f32_to_bf16(float f) {
    unsigned u = __float_as_uint(f);
    unsigned r = u + 0x7fffu + ((u >> 16) & 1u);
    return (unsigned short)(r >> 16);
}
__device__ __forceinline__ float bf16_to_f32(unsigned short s) {
    return __uint_as_float(((unsigned)s) << 16);
}
// 4-wide int8 dot with i32 accumulate: v_dot4_i32_i8 (fallback: manual sext).
__device__ __forceinline__ int dot4(unsigned a, unsigned b, int c) {
#if __has_builtin(__builtin_amdgcn_sdot4)
    return __builtin_amdgcn_sdot4(a, b, c, false);
#else
    c += (int)(signed char)(a)       * (int)(signed char)(b);
    c += (int)(signed char)(a >> 8)  * (int)(signed char)(b >> 8);
    c += (int)(signed char)(a >> 16) * (int)(signed char)(b >> 16);
    c += (int)(signed char)(a >> 24) * (int)(signed char)(b >> 24);
    return c;
#endif
}

// ---------------- prep: A' gather->bf16(pad 320), B' weights->bf16, wtagB bf16[64][400], biasC.
__global__ void prep_kernel(const int* __restrict__ words, const float* __restrict__ emb,
                            const float* __restrict__ wihf, const float* __restrict__ wihb,
                            const float* __restrict__ bfc, const float* __restrict__ bbc,
                            const float* __restrict__ wtag,
                            unsigned short* __restrict__ Abf, unsigned short* __restrict__ Bbf,
                            unsigned short* __restrict__ wtagB, float* __restrict__ biasC) {
    long g = (long)blockIdx.x * 256 + threadIdx.x;
    if (g < NA_T) {
        int i = (int)(g / 320), k = (int)(g % 320);
        float v = (k < E_) ? emb[(long)words[i] * E_ + k] : 0.f;
        Abf[g] = f32_to_bf16(v);
        return;
    }
    g -= NA_T;
    if (g < NB_T) {
        int r = (int)(g / 320), k = (int)(g % 320);
        float v = 0.f;
        if (r < NG_ && k < E_) v = (r < 800) ? wihf[r * E_ + k] : wihb[(r - 800) * E_ + k];
        Bbf[g] = f32_to_bf16(v);
        return;
    }
    g -= NB_T;
    if (g < 25600) {   // wtagB [64][400], rows >=50 zero
        int s = (int)(g / 400), k = (int)(g % 400);
        float v = (s < S_) ? wtag[s * H_ + k] : 0.f;
        wtagB[g] = f32_to_bf16(v);
        return;
    }
    g -= 25600;
    if (g < 1600) { biasC[g] = (g < 800) ? bfc[g] : bbc[g - 800]; return; }
}

// ---------------- w_hh quant: one WAVE per row. Global w8 layout (k-major chunks):
//   [dir] { chunks [j=0..11][row 0..799] uint4 (k=16j..16j+15) at (j*800+row)*16,
//           tails  [row] uint2 (k=192..199) at 153600 + row*8 }   (160,000 B per dir)
__global__ __launch_bounds__(256) void quant_kernel(const float* __restrict__ whh_f,
                                                    const float* __restrict__ whh_b,
                                                    signed char* __restrict__ w8,
                                                    float* __restrict__ invs) {
    int gw = (int)((blockIdx.x * 256 + threadIdx.x) >> 6);
    int lane = threadIdx.x & 63;
    if (gw >= 1600) return;
    int dir = gw / 800, row = gw % 800;
    const float* w = (dir ? whh_b : whh_f) + row * HD_;
    float m = 1e-20f;
    for (int k = lane; k < HD_; k += 64) m = fmaxf(m, fabsf(w[k]));
    for (int off = 32; off; off >>= 1) m = fmaxf(m, __shfl_xor(m, off));
    float s = 127.f / m;
    if (lane < 50) {
        int k0 = lane * 4;
        unsigned pk = 0;
#pragma unroll
        for (int i = 0; i < 4; ++i) {
            int v = (int)rintf(w[k0 + i] * s);
            pk |= ((unsigned)(v & 0xff)) << (8 * i);
        }
        unsigned char* base = (unsigned char*)w8 + dir * 160000;
        if (lane < 48) {
            int j = lane >> 2, wsel = lane & 3;
            *(unsigned*)(base + (size_t)(j * 800 + row) * 16 + wsel * 4) = pk;
        } else {
            *(unsigned*)(base + 153600 + (size_t)row * 8 + (lane - 48) * 4) = pk;
        }
    }
    if (lane == 0) invs[gw] = m / 16129.f;   // m/(127*127)
}

// ---------------- xg GEMM (MFMA bf16), staged from pre-converted bf16 A'/B'. (unchanged)
__global__ __launch_bounds__(256) void xg_gemm(const unsigned short* __restrict__ Abf,
                                               const unsigned short* __restrict__ Bbf,
                                               const float* __restrict__ biasC,
                                               unsigned short* __restrict__ xg) {
    __shared__ unsigned short As[128 * 40];
    __shared__ unsigned short Bs[128 * 40];
    int tid = threadIdx.x;
    int bm = blockIdx.y * 128;
    int bn = blockIdx.x * 128;
    int srow = tid >> 1, half = tid & 1;
    int lane = tid & 63, wave = tid >> 6, r16 = lane & 15, kh = lane >> 4;

    f32x4 acc[2][8];
#pragma unroll
    for (int mi = 0; mi < 2; ++mi)
#pragma unroll
        for (int ni = 0; ni < 8; ++ni) acc[mi][ni] = (f32x4){0.f, 0.f, 0.f, 0.f};

    const unsigned short* Ar = Abf + (long)(bm + srow) * 320;
    const unsigned short* Br = Bbf + (long)(bn + srow) * 320;

    for (int k0 = 0; k0 < 320; k0 += 32) {
#pragma unroll
        for (int j = 0; j < 2; ++j) {
            int off = half * 16 + j * 8;
            *(uint4*)&As[srow * 40 + off] = *(const uint4*)(Ar + k0 + off);
            *(uint4*)&Bs[srow * 40 + off] = *(const uint4*)(Br + k0 + off);
        }
        __syncthreads();
        short8 af[2], bfv[8];
#pragma unroll
        for (int mi = 0; mi < 2; ++mi)
            af[mi] = *(const short8*)&As[(wave * 32 + mi * 16 + r16) * 40 + kh * 8];
#pragma unroll
        for (int ni = 0; ni < 8; ++ni)
            bfv[ni] = *(const short8*)&Bs[(ni * 16 + r16) * 40 + kh * 8];
#pragma unroll
        for (int mi = 0; mi < 2; ++mi)
#pragma unroll
            for (int ni = 0; ni < 8; ++ni)
                acc[mi][ni] = __builtin_amdgcn_mfma_f32_16x16x32_bf16(af[mi], bfv[ni], acc[mi][ni], 0, 0, 0);
        __syncthreads();
    }
#pragma unroll
    for (int ni = 0; ni < 8; ++ni) {
        int g = bn + ni * 16 + r16;
        if (g < NG_) {
            float bias = biasC[g];
#pragma unroll
            for (int mi = 0; mi < 2; ++mi) {
#pragma unroll
                for (int r = 0; r < 4; ++r) {
                    int row = bm + wave * 32 + mi * 16 + kh * 4 + r;
                    xg[(long)row * NG_ + g] = f32_to_bf16(acc[mi][ni][r] + bias);
                }
            }
        }
    }
}

// ---------------- LSTM recurrence: EXACT R13 structure (fastest measured: 155 us).
// 512 thr, 400 active, 2 rows/thread = 100 "VGPRs" of int8 weights, pinned; the
// allocator spills them to scratch and the spill RELOADS stream on the VMEM/L2 pipe
// while h-broadcasts use the LDS pipe — measured-best pipe overlap (R13 vs R12/R14/R15).
// Only change vs R13: lstm output stored as bf16 (feeds MFMA feat kernel).
__global__ __launch_bounds__(512) void lstm_rec(const unsigned short* __restrict__ xg,
                                                const signed char* __restrict__ w8,
                                                const float* __restrict__ invs,
                                                unsigned short* __restrict__ lstm16) {
    __shared__ __align__(16) unsigned char hbuf[208];   // int8 h (200 used, 8 pad)
    __shared__ float a_lds[800];                        // gate activations [q*200+ko]
    int tid = threadIdx.x;
    int dir = blockIdx.x >> 6;
    int b = blockIdx.x & 63;
    bool act = tid < 400;
    int tw = act ? tid : 0;

    const unsigned char* wbase = (const unsigned char*)w8 + dir * 160000;
    uint4 wA[12], wB[12];
    uint2 wAt, wBt;
#pragma unroll
    for (int j = 0; j < 12; ++j) {
        wA[j] = *(const uint4*)(wbase + (size_t)(j * 800 + tw) * 16);
        wB[j] = *(const uint4*)(wbase + (size_t)(j * 800 + tw + 400) * 16);
    }
    wAt = *(const uint2*)(wbase + 153600 + (size_t)tw * 8);
    wBt = *(const uint2*)(wbase + 153600 + (size_t)(tw + 400) * 8);
    // Pin against rematerialization (R4/R5 lesson).
#pragma unroll
    for (int j = 0; j < 12; ++j) {
        asm volatile("" : "+v"(wA[j].x), "+v"(wA[j].y), "+v"(wA[j].z), "+v"(wA[j].w));
        asm volatile("" : "+v"(wB[j].x), "+v"(wB[j].y), "+v"(wB[j].z), "+v"(wB[j].w));
    }
    asm volatile("" : "+v"(wAt.x), "+v"(wAt.y), "+v"(wBt.x), "+v"(wBt.y));

    float invA = act ? invs[dir * 800 + tid] : 0.f;
    float invB = act ? invs[dir * 800 + tid + 400] : 0.f;
    if (tid < 52) ((unsigned*)hbuf)[tid] = 0u;   // h=0 (incl. pad)
    float c = 0.f;
    __syncthreads();

    const uint4* h4c = (const uint4*)hbuf;
    const uint2* ht2 = (const uint2*)(hbuf + 192);
    const unsigned short* xbase = xg + (long)b * L_ * NG_ + dir * 800;

    int t0 = dir ? (L_ - 1) : 0;
    float xa = act ? bf16_to_f32(xbase[(long)t0 * NG_ + tid]) : 0.f;
    float xb = act ? bf16_to_f32(xbase[(long)t0 * NG_ + tid + 400]) : 0.f;

    for (int step = 0; step < L_; ++step) {
        int t = dir ? (L_ - 1 - step) : step;
        float xa_n = 0.f, xb_n = 0.f;
        if (act && step + 1 < L_) {
            int tn = dir ? (t - 1) : (t + 1);
            xa_n = bf16_to_f32(xbase[(long)tn * NG_ + tid]);
            xb_n = bf16_to_f32(xbase[(long)tn * NG_ + tid + 400]);
        }
        if (act) {
            int di0 = 0, di1 = 0;
#pragma unroll
            for (int j = 0; j < 12; ++j) {
                uint4 hh = h4c[j];
                di0 = dot4(wA[j].x, hh.x, di0); di0 = dot4(wA[j].y, hh.y, di0);
                di0 = dot4(wA[j].z, hh.z, di0); di0 = dot4(wA[j].w, hh.w, di0);
                di1 = dot4(wB[j].x, hh.x, di1); di1 = dot4(wB[j].y, hh.y, di1);
                di1 = dot4(wB[j].z, hh.z, di1); di1 = dot4(wB[j].w, hh.w, di1);
            }
            {
                uint2 hh = ht2[0];
                di0 = dot4(wAt.x, hh.x, di0); di0 = dot4(wAt.y, hh.y, di0);
                di1 = dot4(wBt.x, hh.x, di1); di1 = dot4(wBt.y, hh.y, di1);
            }
            float pa = xa + (float)di0 * invA;   // i (t<200) / f
            float pb = xb + (float)di1 * invB;   // g (t<200) / o
            a_lds[tid] = 1.f / (1.f + __expf(-pa));
            if (tid < 200) {
                float e = __expf(-2.f * pb);                     // tanh(g)
                a_lds[400 + tid] = 2.f / (1.f + e) - 1.f;
            } else {
                a_lds[400 + tid] = 1.f / (1.f + __expf(-pb));    // sig(o)
            }
        }
        __syncthreads();
        if (tid < HD_) {
            float ig = a_lds[tid];
            float fg = a_lds[200 + tid];
            float gg = a_lds[400 + tid];
            float og = a_lds[600 + tid];
            c = fg * c + ig * gg;
            float ec = __expf(-2.f * c);
            float hn = og * (2.f / (1.f + ec) - 1.f);
            ((signed char*)hbuf)[tid] = (signed char)(int)rintf(hn * 127.f);
            lstm16[((long)(b * L_ + t)) * H_ + dir * HD_ + tid] = f32_to_bf16(hn);
        }
        xa = xa_n; xb = xb_n;
        __syncthreads();
    }
}

// ---------------- features via MFMA: feats[8192][50] = lstm16[8192][400] @ wtagB^T + btag.
__global__ __launch_bounds__(256) void feat_kernel(const unsigned short* __restrict__ lstm16,
                                                   const unsigned short* __restrict__ wtagB,
                                                   const float* __restrict__ btag,
                                                   float* __restrict__ feats) {
    __shared__ unsigned short As[128 * 40];
    __shared__ unsigned short Bs[64 * 40];
    int tid = threadIdx.x;
    int bm = blockIdx.x * 128;
    int srow = tid >> 1, half = tid & 1;
    int lane = tid & 63, wave = tid >> 6, r16 = lane & 15, kh = lane >> 4;

    f32x4 acc[2][4];
#pragma unroll
    for (int mi = 0; mi < 2; ++mi)
#pragma unroll
        for (int ni = 0; ni < 4; ++ni) acc[mi][ni] = (f32x4){0.f, 0.f, 0.f, 0.f};

    const unsigned short* Ar = lstm16 + (long)(bm + srow) * 400;
    const unsigned short* Br = wtagB + (long)srow * 400;

    for (int k0 = 0; k0 < 400; k0 += 32) {
#pragma unroll
        for (int j = 0; j < 2; ++j) {
            int off = half * 16 + j * 8;
            bool kv = (k0 + off + 8 <= 400);
            uint4 z = make_uint4(0u, 0u, 0u, 0u);
            *(uint4*)&As[srow * 40 + off] = kv ? *(const uint4*)(Ar + k0 + off) : z;
            if (srow < 64)
                *(uint4*)&Bs[srow * 40 + off] = kv ? *(const uint4*)(Br + k0 + off) : z;
        }
        __syncthreads();
        short8 af[2], bfv[4];
#pragma unroll
        for (int mi = 0; mi < 2; ++mi)
            af[mi] = *(const short8*)&As[(wave * 32 + mi * 16 + r16) * 40 + kh * 8];
#pragma unroll
        for (int ni = 0; ni < 4; ++ni)
            bfv[ni] = *(const short8*)&Bs[(ni * 16 + r16) * 40 + kh * 8];
#pragma unroll
        for (int mi = 0; mi < 2; ++mi)
#pragma unroll
            for (int ni = 0; ni < 4; ++ni)
                acc[mi][ni] = __builtin_amdgcn_mfma_f32_16x16x32_bf16(af[mi], bfv[ni], acc[mi][ni], 0, 0, 0);
        __syncthreads();
    }
#pragma unroll
    for (int ni = 0; ni < 4; ++ni) {
        int g = ni * 16 + r16;
        if (g < S_) {
            float bias = btag[g];
#pragma unroll
            for (int mi = 0; mi < 2; ++mi) {
#pragma unroll
                for (int r = 0; r < 4; ++r) {
                    int row = bm + wave * 32 + mi * 16 + kh * 4 + r;
                    feats[(long)row * S_ + g] = acc[mi][ni][r] + bias;
                }
            }
        }
    }
}

// ---------------- CRF forward + labeled score (per-batch partials, no atomics)
__global__ __launch_bounds__(512) void crf_kernel(const float* __restrict__ feats,
                                                  const float* __restrict__ trans,
                                                  const int* __restrict__ tags,
                                                  const int* __restrict__ seqlens,
                                                  float* __restrict__ part) {
    __shared__ float Tt[S_ * S_];   // Tt[j*50+i] = trans[i*50+j]
    __shared__ float alpha[S_];
    __shared__ float lastal[S_];
    __shared__ int tg[L_];
    int tid = threadIdx.x;
    int b = blockIdx.x;
    for (int idx = tid; idx < S_ * S_; idx += 512) {
        int j = idx / S_, i = idx % S_;
        Tt[idx] = trans[i * S_ + j];
    }
    if (tid < L_) tg[tid] = tags[b * L_ + tid];
    int slen = seqlens[b];
    const float* fb = feats + (long)b * L_ * S_;
    __syncthreads();
    if (tid < S_) {
        float a = Tt[tid * S_ + START_] + fb[tid];
        alpha[tid] = a;
        if (slen == 1) lastal[tid] = a;
    }
    __syncthreads();
    int j = tid >> 3, sub = tid & 7;
    bool jact = j < S_;
    for (int t = 1; t < L_; ++t) {
        float anew = 0.f;
        if (jact) {
            float m = -1e30f;
            for (int i = sub; i < S_; i += 8) m = fmaxf(m, alpha[i] + Tt[j * S_ + i]);
            m = fmaxf(m, __shfl_xor(m, 1));
            m = fmaxf(m, __shfl_xor(m, 2));
            m = fmaxf(m, __shfl_xor(m, 4));
            float s = 0.f;
            for (int i = sub; i < S_; i += 8) s += __expf(alpha[i] + Tt[j * S_ + i] - m);
            s += __shfl_xor(s, 1);
            s += __shfl_xor(s, 2);
            s += __shfl_xor(s, 4);
            anew = m + __logf(s) + fb[t * S_ + j];
        }
        __syncthreads();
        if (jact && sub == 0) {
            alpha[j] = anew;
            if (t == slen - 1) lastal[j] = anew;
        }
        __syncthreads();
    }
    if (tid < 64) {
        float la = (tid < S_) ? (lastal[tid] + Tt[END_ * S_ + tid]) : -1e30f;
        float m = la;
        for (int off = 32; off; off >>= 1) m = fmaxf(m, __shfl_xor(m, off));
        float e = (tid < S_) ? __expf(la - m) : 0.f;
        for (int off = 32; off; off >>= 1) e += __shfl_xor(e, off);
        float unl = m + __logf(e);
        float lab = 0.f;
        for (int tt = tid; tt < L_; tt += 64) {
            if (tt == 0) {
                lab += Tt[tg[0] * S_ + START_] + fb[tg[0]];
            } else if (tt < slen) {
                lab += Tt[tg[tt] * S_ + tg[tt - 1]] + fb[tt * S_ + tg[tt]];
            }
        }
        if (tid == 0) lab += Tt[END_ * S_ + tg[slen - 1]];
        for (int off = 32; off; off >>= 1) lab += __shfl_xor(lab, off);
        if (tid == 0) part[b] = unl - lab;
    }
}

// ---------------- final: deterministic fixed-order sum of 64 partials
__global__ void fin_kernel(const float* __restrict__ part, float* __restrict__ out) {
    float s = 0.f;
    for (int i = 0; i < B_; ++i) s += part[i];
    out[0] = s;
}

extern "C" void kernel_launch(void* const* d_in, const int* in_sizes, int n_in,
                              void* d_out, int out_size, void* d_ws, size_t ws_size,
                              hipStream_t stream) {
    const int*   words = (const int*)d_in[0];
    const int*   slens = (const int*)d_in[1];
    // d_in[2] = masks: semantically (t < seq_len); not read.
    const int*   tags  = (const int*)d_in[3];
    const float* emb   = (const float*)d_in[4];
    const float* wihf  = (const float*)d_in[5];
    const float* whhf  = (const float*)d_in[6];
    const float* bf    = (const float*)d_in[7];
    const float* wihb  = (const float*)d_in[8];
    const float* whhb  = (const float*)d_in[9];
    const float* bb    = (const float*)d_in[10];
    const float* wtag  = (const float*)d_in[11];
    const float* btag  = (const float*)d_in[12];
    const float* trans = (const float*)d_in[13];

    char* ws = (char*)d_ws;
    unsigned short* xg     = (unsigned short*)(ws + OFF_XG);
    unsigned short* lstm16 = (unsigned short*)(ws + OFF_LSTM);
    unsigned short* Abf    = (unsigned short*)(ws + OFF_ABF);  // prep -> xg (overlaid by lstm16)
    unsigned short* Bbf    = (unsigned short*)(ws + OFF_BBF);  // prep -> xg (overlaid by lstm16)
    signed char*    w8     = (signed char*)(ws + OFF_SH);      // quant -> lstm
    float*          fts    = (float*)(ws + OFF_SH);            // feat -> crf (time-shared with w8)
    float*          invs   = (float*)(ws + OFF_INV);
    unsigned short* wtagB  = (unsigned short*)(ws + OFF_WTB);
    float*          biaC   = (float*)(ws + OFF_BIA);
    float*          part   = (float*)(ws + OFF_PART);
    float*          out    = (float*)d_out;

    prep_kernel<<<PREP_BLOCKS, 256, 0, stream>>>(words, emb, wihf, wihb, bf, bb,
                                                 wtag, Abf, Bbf, wtagB, biaC);
    quant_kernel<<<400, 256, 0, stream>>>(whhf, whhb, w8, invs);
    xg_gemm<<<dim3(13, 64), 256, 0, stream>>>(Abf, Bbf, biaC, xg);
    lstm_rec<<<128, 512, 0, stream>>>(xg, w8, invs, lstm16);
    feat_kernel<<<64, 256, 0, stream>>>(lstm16, wtagB, btag, fts);
    crf_kernel<<<64, 512, 0, stream>>>(fts, trans, tags, slens, part);
    fin_kernel<<<1, 1, 0, stream>>>(part, out);
}

// Round 17
// 353.552 us; speedup vs baseline: 1.2940x; 1.0244x over previous
//
#include <hip/hip_runtime.h>
#include <hip/hip_fp16.h>

#define B_ 64
#define L_ 128
#define E_ 300
#define HD_ 200
#define H_ 400
#define S_ 50
#define START_ 48
#define END_ 49
#define NG_ 1600
#define BL_ 8192

// ---- ws layout (bytes) ----
#define OFF_XG   0ull                          // bf16 [8192][1600]  26,214,400
#define OFF_LSTM 26214400ull                   // bf16 [8192][400]  6,553,600 (lstm16; overlays A'/B')
#define OFF_ABF  OFF_LSTM                      // bf16 [8192][320]    5,242,880 (prep->xg)
#define OFF_BBF  (OFF_LSTM + 5242880ull)       // bf16 [1664][320]    1,064,960 (prep->xg)
#define OFF_SH   (OFF_LSTM + 13107200ull)      // max(w8 320,000 ; feats 1,638,400)
#define OFF_INV  (OFF_SH + 1638400ull)         // f32 [1600]  6,400
#define OFF_WTB  (OFF_INV + 6400ull)           // bf16 [64][400] 51,200 (wtagB)
#define OFF_BIA  (OFF_WTB + 80000ull)          // f32 [1600]  6,400
#define OFF_PART (OFF_BIA + 6400ull)           // f32 [64] per-batch partials

#define NA_T 2621440   // 8192*320
#define NB_T 532480    // 1664*320
// prep items = NA_T + NB_T + 25600 (wtagB) + 1600 (biasC) = 3,181,120
// grid 12427*256 = 3,181,312 >= 3,181,120
#define PREP_BLOCKS 12427

typedef __attribute__((ext_vector_type(8))) short short8;
typedef __attribute__((ext_vector_type(4))) float f32x4;

__device__ __forceinline__ unsigned short f32_to_bf16(float f) {
    unsigned u = __float_as_uint(f);
    unsigned r = u + 0x7fffu + ((u >> 16) & 1u);
    return (unsigned short)(r >> 16);
}
__device__ __forceinline__ float bf16_to_f32(unsigned short s) {
    return __uint_as_float(((unsigned)s) << 16);
}
// 4-wide int8 dot with i32 accumulate: v_dot4_i32_i8 (fallback: manual sext).
__device__ __forceinline__ int dot4(unsigned a, unsigned b, int c) {
#if __has_builtin(__builtin_amdgcn_sdot4)
    return __builtin_amdgcn_sdot4(a, b, c, false);
#else
    c += (int)(signed char)(a)       * (int)(signed char)(b);
    c += (int)(signed char)(a >> 8)  * (int)(signed char)(b >> 8);
    c += (int)(signed char)(a >> 16) * (int)(signed char)(b >> 16);
    c += (int)(signed char)(a >> 24) * (int)(signed char)(b >> 24);
    return c;
#endif
}

// ---------------- prep: A' gather->bf16(pad 320), B' weights->bf16, wtagB bf16[64][400], biasC.
__global__ void prep_kernel(const int* __restrict__ words, const float* __restrict__ emb,
                            const float* __restrict__ wihf, const float* __restrict__ wihb,
                            const float* __restrict__ bfc, const float* __restrict__ bbc,
                            const float* __restrict__ wtag,
                            unsigned short* __restrict__ Abf, unsigned short* __restrict__ Bbf,
                            unsigned short* __restrict__ wtagB, float* __restrict__ biasC) {
    long g = (long)blockIdx.x * 256 + threadIdx.x;
    if (g < NA_T) {
        int i = (int)(g / 320), k = (int)(g % 320);
        float v = (k < E_) ? emb[(long)words[i] * E_ + k] : 0.f;
        Abf[g] = f32_to_bf16(v);
        return;
    }
    g -= NA_T;
    if (g < NB_T) {
        int r = (int)(g / 320), k = (int)(g % 320);
        float v = 0.f;
        if (r < NG_ && k < E_) v = (r < 800) ? wihf[r * E_ + k] : wihb[(r - 800) * E_ + k];
        Bbf[g] = f32_to_bf16(v);
        return;
    }
    g -= NB_T;
    if (g < 25600) {   // wtagB [64][400], rows >=50 zero
        int s = (int)(g / 400), k = (int)(g % 400);
        float v = (s < S_) ? wtag[s * H_ + k] : 0.f;
        wtagB[g] = f32_to_bf16(v);
        return;
    }
    g -= 25600;
    if (g < 1600) { biasC[g] = (g < 800) ? bfc[g] : bbc[g - 800]; return; }
}

// ---------------- w_hh quant: one WAVE per row. Global w8 layout (k-major chunks):
//   [dir] { chunks [j=0..11][row 0..799] uint4 (k=16j..16j+15) at (j*800+row)*16,
//           tails  [row] uint2 (k=192..199) at 153600 + row*8 }   (160,000 B per dir)
__global__ __launch_bounds__(256) void quant_kernel(const float* __restrict__ whh_f,
                                                    const float* __restrict__ whh_b,
                                                    signed char* __restrict__ w8,
                                                    float* __restrict__ invs) {
    int gw = (int)((blockIdx.x * 256 + threadIdx.x) >> 6);
    int lane = threadIdx.x & 63;
    if (gw >= 1600) return;
    int dir = gw / 800, row = gw % 800;
    const float* w = (dir ? whh_b : whh_f) + row * HD_;
    float m = 1e-20f;
    for (int k = lane; k < HD_; k += 64) m = fmaxf(m, fabsf(w[k]));
    for (int off = 32; off; off >>= 1) m = fmaxf(m, __shfl_xor(m, off));
    float s = 127.f / m;
    if (lane < 50) {
        int k0 = lane * 4;
        unsigned pk = 0;
#pragma unroll
        for (int i = 0; i < 4; ++i) {
            int v = (int)rintf(w[k0 + i] * s);
            pk |= ((unsigned)(v & 0xff)) << (8 * i);
        }
        unsigned char* base = (unsigned char*)w8 + dir * 160000;
        if (lane < 48) {
            int j = lane >> 2, wsel = lane & 3;
            *(unsigned*)(base + (size_t)(j * 800 + row) * 16 + wsel * 4) = pk;
        } else {
            *(unsigned*)(base + 153600 + (size_t)row * 8 + (lane - 48) * 4) = pk;
        }
    }
    if (lane == 0) invs[gw] = m / 16129.f;   // m/(127*127)
}

// ---------------- xg GEMM (MFMA bf16), staged from pre-converted bf16 A'/B'. (unchanged)
__global__ __launch_bounds__(256) void xg_gemm(const unsigned short* __restrict__ Abf,
                                               const unsigned short* __restrict__ Bbf,
                                               const float* __restrict__ biasC,
                                               unsigned short* __restrict__ xg) {
    __shared__ unsigned short As[128 * 40];
    __shared__ unsigned short Bs[128 * 40];
    int tid = threadIdx.x;
    int bm = blockIdx.y * 128;
    int bn = blockIdx.x * 128;
    int srow = tid >> 1, half = tid & 1;
    int lane = tid & 63, wave = tid >> 6, r16 = lane & 15, kh = lane >> 4;

    f32x4 acc[2][8];
#pragma unroll
    for (int mi = 0; mi < 2; ++mi)
#pragma unroll
        for (int ni = 0; ni < 8; ++ni) acc[mi][ni] = (f32x4){0.f, 0.f, 0.f, 0.f};

    const unsigned short* Ar = Abf + (long)(bm + srow) * 320;
    const unsigned short* Br = Bbf + (long)(bn + srow) * 320;

    for (int k0 = 0; k0 < 320; k0 += 32) {
#pragma unroll
        for (int j = 0; j < 2; ++j) {
            int off = half * 16 + j * 8;
            *(uint4*)&As[srow * 40 + off] = *(const uint4*)(Ar + k0 + off);
            *(uint4*)&Bs[srow * 40 + off] = *(const uint4*)(Br + k0 + off);
        }
        __syncthreads();
        short8 af[2], bfv[8];
#pragma unroll
        for (int mi = 0; mi < 2; ++mi)
            af[mi] = *(const short8*)&As[(wave * 32 + mi * 16 + r16) * 40 + kh * 8];
#pragma unroll
        for (int ni = 0; ni < 8; ++ni)
            bfv[ni] = *(const short8*)&Bs[(ni * 16 + r16) * 40 + kh * 8];
#pragma unroll
        for (int mi = 0; mi < 2; ++mi)
#pragma unroll
            for (int ni = 0; ni < 8; ++ni)
                acc[mi][ni] = __builtin_amdgcn_mfma_f32_16x16x32_bf16(af[mi], bfv[ni], acc[mi][ni], 0, 0, 0);
        __syncthreads();
    }
#pragma unroll
    for (int ni = 0; ni < 8; ++ni) {
        int g = bn + ni * 16 + r16;
        if (g < NG_) {
            float bias = biasC[g];
#pragma unroll
            for (int mi = 0; mi < 2; ++mi) {
#pragma unroll
                for (int r = 0; r < 4; ++r) {
                    int row = bm + wave * 32 + mi * 16 + kh * 4 + r;
                    xg[(long)row * NG_ + g] = f32_to_bf16(acc[mi][ni][r] + bias);
                }
            }
        }
    }
}

// ---------------- LSTM recurrence: int8 weights ~fully register-resident.
// Allocator ledger: 832thr -> cap 60-64 (R7/R8 observed). R7's f16 needed 100 VGPR ->
// full spill (213us). INT8 needs only 50 VGPR/row (12 uint4 + 1 uint2): demand ~70,
// over cap by ~6-10 -> at most a sliver spills (~25-40B/thread/step vs R13's 400B).
// 832 thr, 800 active, ONE gate-row each (rows: q*200+ko, q=0i 1f 2g 3o = w_hh order).
// Per step: 13 h-broadcast LDS reads + 50 v_dot4 + 1 transcendental.
__global__ __launch_bounds__(832) void lstm_rec(const unsigned short* __restrict__ xg,
                                                const signed char* __restrict__ w8,
                                                const float* __restrict__ invs,
                                                unsigned short* __restrict__ lstm16) {
    __shared__ __align__(16) unsigned char hbuf[256];   // int8 h (200 used)
    __shared__ float a_lds[800];                        // gate activations [q*200+ko]
    int tid = threadIdx.x;
    int dir = blockIdx.x >> 6;
    int b = blockIdx.x & 63;
    bool act = tid < 800;
    int tw = act ? tid : 0;
    int q = tid / 200;   // 0=i 1=f 2=g 3=o

    const unsigned char* wbase = (const unsigned char*)w8 + dir * 160000;
    uint4 wA[12];
    uint2 wAt;
#pragma unroll
    for (int j = 0; j < 12; ++j)
        wA[j] = *(const uint4*)(wbase + (size_t)(j * 800 + tw) * 16);
    wAt = *(const uint2*)(wbase + 153600 + (size_t)tw * 8);
    // Pin against rematerialization (R4/R5 lesson).
#pragma unroll
    for (int j = 0; j < 12; ++j)
        asm volatile("" : "+v"(wA[j].x), "+v"(wA[j].y), "+v"(wA[j].z), "+v"(wA[j].w));
    asm volatile("" : "+v"(wAt.x), "+v"(wAt.y));

    float invsc = act ? invs[dir * 800 + tid] : 0.f;
    if (tid < 64) ((unsigned*)hbuf)[tid] = 0u;   // h=0
    float c = 0.f;
    __syncthreads();

    const uint4* h4c = (const uint4*)hbuf;
    const uint2* ht2 = (const uint2*)(hbuf + 192);
    const unsigned short* xbase = xg + (long)b * L_ * NG_ + dir * 800;

    int t0 = dir ? (L_ - 1) : 0;
    float x = act ? bf16_to_f32(xbase[(long)t0 * NG_ + tid]) : 0.f;

    for (int step = 0; step < L_; ++step) {
        int t = dir ? (L_ - 1 - step) : step;
        float x_n = 0.f;
        if (act && step + 1 < L_) {
            int tn = dir ? (t - 1) : (t + 1);
            x_n = bf16_to_f32(xbase[(long)tn * NG_ + tid]);
        }
        if (act) {
            int di = 0;
#pragma unroll
            for (int j = 0; j < 12; ++j) {
                uint4 hh = h4c[j];
                di = dot4(wA[j].x, hh.x, di); di = dot4(wA[j].y, hh.y, di);
                di = dot4(wA[j].z, hh.z, di); di = dot4(wA[j].w, hh.w, di);
            }
            {
                uint2 hh = ht2[0];
                di = dot4(wAt.x, hh.x, di); di = dot4(wAt.y, hh.y, di);
            }
            float p = x + (float)di * invsc;
            float av;
            if (q == 2) {
                float e = __expf(-2.f * p);          // tanh(g)
                av = 2.f / (1.f + e) - 1.f;
            } else {
                av = 1.f / (1.f + __expf(-p));       // sigmoid (i,f,o)
            }
            a_lds[tid] = av;
        }
        __syncthreads();
        if (tid < HD_) {
            float ig = a_lds[tid];
            float fg = a_lds[200 + tid];
            float gg = a_lds[400 + tid];
            float og = a_lds[600 + tid];
            c = fg * c + ig * gg;
            float ec = __expf(-2.f * c);
            float hn = og * (2.f / (1.f + ec) - 1.f);
            ((signed char*)hbuf)[tid] = (signed char)(int)rintf(hn * 127.f);
            lstm16[((long)(b * L_ + t)) * H_ + dir * HD_ + tid] = f32_to_bf16(hn);
        }
        x = x_n;
        __syncthreads();
    }
}

// ---------------- features via MFMA: feats[8192][50] = lstm16[8192][400] @ wtagB^T + btag.
__global__ __launch_bounds__(256) void feat_kernel(const unsigned short* __restrict__ lstm16,
                                                   const unsigned short* __restrict__ wtagB,
                                                   const float* __restrict__ btag,
                                                   float* __restrict__ feats) {
    __shared__ unsigned short As[128 * 40];
    __shared__ unsigned short Bs[64 * 40];
    int tid = threadIdx.x;
    int bm = blockIdx.x * 128;
    int srow = tid >> 1, half = tid & 1;
    int lane = tid & 63, wave = tid >> 6, r16 = lane & 15, kh = lane >> 4;

    f32x4 acc[2][4];
#pragma unroll
    for (int mi = 0; mi < 2; ++mi)
#pragma unroll
        for (int ni = 0; ni < 4; ++ni) acc[mi][ni] = (f32x4){0.f, 0.f, 0.f, 0.f};

    const unsigned short* Ar = lstm16 + (long)(bm + srow) * 400;
    const unsigned short* Br = wtagB + (long)srow * 400;

    for (int k0 = 0; k0 < 400; k0 += 32) {
#pragma unroll
        for (int j = 0; j < 2; ++j) {
            int off = half * 16 + j * 8;
            bool kv = (k0 + off + 8 <= 400);
            uint4 z = make_uint4(0u, 0u, 0u, 0u);
            *(uint4*)&As[srow * 40 + off] = kv ? *(const uint4*)(Ar + k0 + off) : z;
            if (srow < 64)
                *(uint4*)&Bs[srow * 40 + off] = kv ? *(const uint4*)(Br + k0 + off) : z;
        }
        __syncthreads();
        short8 af[2], bfv[4];
#pragma unroll
        for (int mi = 0; mi < 2; ++mi)
            af[mi] = *(const short8*)&As[(wave * 32 + mi * 16 + r16) * 40 + kh * 8];
#pragma unroll
        for (int ni = 0; ni < 4; ++ni)
            bfv[ni] = *(const short8*)&Bs[(ni * 16 + r16) * 40 + kh * 8];
#pragma unroll
        for (int mi = 0; mi < 2; ++mi)
#pragma unroll
            for (int ni = 0; ni < 4; ++ni)
                acc[mi][ni] = __builtin_amdgcn_mfma_f32_16x16x32_bf16(af[mi], bfv[ni], acc[mi][ni], 0, 0, 0);
        __syncthreads();
    }
#pragma unroll
    for (int ni = 0; ni < 4; ++ni) {
        int g = ni * 16 + r16;
        if (g < S_) {
            float bias = btag[g];
#pragma unroll
            for (int mi = 0; mi < 2; ++mi) {
#pragma unroll
                for (int r = 0; r < 4; ++r) {
                    int row = bm + wave * 32 + mi * 16 + kh * 4 + r;
                    feats[(long)row * S_ + g] = acc[mi][ni][r] + bias;
                }
            }
        }
    }
}

// ---------------- CRF forward + labeled score (per-batch partials, no atomics)
__global__ __launch_bounds__(512) void crf_kernel(const float* __restrict__ feats,
                                                  const float* __restrict__ trans,
                                                  const int* __restrict__ tags,
                                                  const int* __restrict__ seqlens,
                                                  float* __restrict__ part) {
    __shared__ float Tt[S_ * S_];   // Tt[j*50+i] = trans[i*50+j]
    __shared__ float alpha[S_];
    __shared__ float lastal[S_];
    __shared__ int tg[L_];
    int tid = threadIdx.x;
    int b = blockIdx.x;
    for (int idx = tid; idx < S_ * S_; idx += 512) {
        int j = idx / S_, i = idx % S_;
        Tt[idx] = trans[i * S_ + j];
    }
    if (tid < L_) tg[tid] = tags[b * L_ + tid];
    int slen = seqlens[b];
    const float* fb = feats + (long)b * L_ * S_;
    __syncthreads();
    if (tid < S_) {
        float a = Tt[tid * S_ + START_] + fb[tid];
        alpha[tid] = a;
        if (slen == 1) lastal[tid] = a;
    }
    __syncthreads();
    int j = tid >> 3, sub = tid & 7;
    bool jact = j < S_;
    for (int t = 1; t < L_; ++t) {
        float anew = 0.f;
        if (jact) {
            float m = -1e30f;
            for (int i = sub; i < S_; i += 8) m = fmaxf(m, alpha[i] + Tt[j * S_ + i]);
            m = fmaxf(m, __shfl_xor(m, 1));
            m = fmaxf(m, __shfl_xor(m, 2));
            m = fmaxf(m, __shfl_xor(m, 4));
            float s = 0.f;
            for (int i = sub; i < S_; i += 8) s += __expf(alpha[i] + Tt[j * S_ + i] - m);
            s += __shfl_xor(s, 1);
            s += __shfl_xor(s, 2);
            s += __shfl_xor(s, 4);
            anew = m + __logf(s) + fb[t * S_ + j];
        }
        __syncthreads();
        if (jact && sub == 0) {
            alpha[j] = anew;
            if (t == slen - 1) lastal[j] = anew;
        }
        __syncthreads();
    }
    if (tid < 64) {
        float la = (tid < S_) ? (lastal[tid] + Tt[END_ * S_ + tid]) : -1e30f;
        float m = la;
        for (int off = 32; off; off >>= 1) m = fmaxf(m, __shfl_xor(m, off));
        float e = (tid < S_) ? __expf(la - m) : 0.f;
        for (int off = 32; off; off >>= 1) e += __shfl_xor(e, off);
        float unl = m + __logf(e);
        float lab = 0.f;
        for (int tt = tid; tt < L_; tt += 64) {
            if (tt == 0) {
                lab += Tt[tg[0] * S_ + START_] + fb[tg[0]];
            } else if (tt < slen) {
                lab += Tt[tg[tt] * S_ + tg[tt - 1]] + fb[tt * S_ + tg[tt]];
            }
        }
        if (tid == 0) lab += Tt[END_ * S_ + tg[slen - 1]];
        for (int off = 32; off; off >>= 1) lab += __shfl_xor(lab, off);
        if (tid == 0) part[b] = unl - lab;
    }
}

// ---------------- final: deterministic fixed-order sum of 64 partials
__global__ void fin_kernel(const float* __restrict__ part, float* __restrict__ out) {
    float s = 0.f;
    for (int i = 0; i < B_; ++i) s += part[i];
    out[0] = s;
}

extern "C" void kernel_launch(void* const* d_in, const int* in_sizes, int n_in,
                              void* d_out, int out_size, void* d_ws, size_t ws_size,
                              hipStream_t stream) {
    const int*   words = (const int*)d_in[0];
    const int*   slens = (const int*)d_in[1];
    // d_in[2] = masks: semantically (t < seq_len); not read.
    const int*   tags  = (const int*)d_in[3];
    const float* emb   = (const float*)d_in[4];
    const float* wihf  = (const float*)d_in[5];
    const float* whhf  = (const float*)d_in[6];
    const float* bf    = (const float*)d_in[7];
    const float* wihb  = (const float*)d_in[8];
    const float* whhb  = (const float*)d_in[9];
    const float* bb    = (const float*)d_in[10];
    const float* wtag  = (const float*)d_in[11];
    const float* btag  = (const float*)d_in[12];
    const float* trans = (const float*)d_in[13];

    char* ws = (char*)d_ws;
    unsigned short* xg     = (unsigned short*)(ws + OFF_XG);
    unsigned short* lstm16 = (unsigned short*)(ws + OFF_LSTM);
    unsigned short* Abf    = (unsigned short*)(ws + OFF_ABF);  // prep -> xg (overlaid by lstm16)
    unsigned short* Bbf    = (unsigned short*)(ws + OFF_BBF);  // prep -> xg (overlaid by lstm16)
    signed char*    w8     = (signed char*)(ws + OFF_SH);      // quant -> lstm
    float*          fts    = (float*)(ws + OFF_SH);            // feat -> crf (time-shared with w8)
    float*          invs   = (float*)(ws + OFF_INV);
    unsigned short* wtagB  = (unsigned short*)(ws + OFF_WTB);
    float*          biaC   = (float*)(ws + OFF_BIA);
    float*          part   = (float*)(ws + OFF_PART);
    float*          out    = (float*)d_out;

    prep_kernel<<<PREP_BLOCKS, 256, 0, stream>>>(words, emb, wihf, wihb, bf, bb,
                                                 wtag, Abf, Bbf, wtagB, biaC);
    quant_kernel<<<400, 256, 0, stream>>>(whhf, whhb, w8, invs);
    xg_gemm<<<dim3(13, 64), 256, 0, stream>>>(Abf, Bbf, biaC, xg);
    lstm_rec<<<128, 832, 0, stream>>>(xg, w8, invs, lstm16);
    feat_kernel<<<64, 256, 0, stream>>>(lstm16, wtagB, btag, fts);
    crf_kernel<<<64, 512, 0, stream>>>(fts, trans, tags, slens, part);
    fin_kernel<<<1, 1, 0, stream>>>(part, out);
}

// Round 18
// 314.737 us; speedup vs baseline: 1.4536x; 1.1233x over previous
//
#include <hip/hip_runtime.h>
#include <hip/hip_fp16.h>

#define B_ 64
#define L_ 128
#define E_ 300
#define HD_ 200
#define H_ 400
#define S_ 50
#define START_ 48
#define END_ 49
#define NG_ 1600
#define BL_ 8192

// ---- ws layout (bytes) ----
#define OFF_XG   0ull                          // bf16 [8192][1600]  26,214,400
#define OFF_LSTM 26214400ull                   // bf16 [8192][400]  6,553,600 (lstm16; overlays A'/B')
#define OFF_ABF  OFF_LSTM                      // bf16 [8192][320]    5,242,880 (prep->xg)
#define OFF_BBF  (OFF_LSTM + 5242880ull)       // bf16 [1664][320]    1,064,960 (prep->xg)
#define OFF_SH   (OFF_LSTM + 13107200ull)      // max(w8 320,000 ; feats 1,638,400)
#define OFF_INV  (OFF_SH + 1638400ull)         // f32 [1600]  6,400
#define OFF_WTB  (OFF_INV + 6400ull)           // bf16 [64][400] 51,200 (wtagB)
#define OFF_BIA  (OFF_WTB + 80000ull)          // f32 [1600]  6,400
#define OFF_PART (OFF_BIA + 6400ull)           // f32 [64] per-batch partials

#define NA_T 2621440   // 8192*320
#define NB_T 532480    // 1664*320
// prep items = NA_T + NB_T + 25600 (wtagB) + 1600 (biasC) = 3,181,120
// grid 12427*256 = 3,181,312 >= 3,181,120
#define PREP_BLOCKS 12427

typedef __attribute__((ext_vector_type(8))) short short8;
typedef __attribute__((ext_vector_type(4))) float f32x4;

__device__ __forceinline__ unsigned short f32_to_bf16(float f) {
    unsigned u = __float_as_uint(f);
    unsigned r = u + 0x7fffu + ((u >> 16) & 1u);
    return (unsigned short)(r >> 16);
}
__device__ __forceinline__ float bf16_to_f32(unsigned short s) {
    return __uint_as_float(((unsigned)s) << 16);
}
// 4-wide int8 dot with i32 accumulate: v_dot4_i32_i8 (fallback: manual sext).
__device__ __forceinline__ int dot4(unsigned a, unsigned b, int c) {
#if __has_builtin(__builtin_amdgcn_sdot4)
    return __builtin_amdgcn_sdot4(a, b, c, false);
#else
    c += (int)(signed char)(a)       * (int)(signed char)(b);
    c += (int)(signed char)(a >> 8)  * (int)(signed char)(b >> 8);
    c += (int)(signed char)(a >> 16) * (int)(signed char)(b >> 16);
    c += (int)(signed char)(a >> 24) * (int)(signed char)(b >> 24);
    return c;
#endif
}
// wave-uniform broadcast of lane l's value (VALU readlane; fallback shfl)
__device__ __forceinline__ float rlanef(float v, int l) {
#if __has_builtin(__builtin_amdgcn_readlane)
    return __uint_as_float(__builtin_amdgcn_readlane(__float_as_uint(v), l));
#else
    return __shfl(v, l, 64);
#endif
}

// ---------------- prep: A' gather->bf16(pad 320), B' weights->bf16, wtagB bf16[64][400], biasC.
__global__ void prep_kernel(const int* __restrict__ words, const float* __restrict__ emb,
                            const float* __restrict__ wihf, const float* __restrict__ wihb,
                            const float* __restrict__ bfc, const float* __restrict__ bbc,
                            const float* __restrict__ wtag,
                            unsigned short* __restrict__ Abf, unsigned short* __restrict__ Bbf,
                            unsigned short* __restrict__ wtagB, float* __restrict__ biasC) {
    long g = (long)blockIdx.x * 256 + threadIdx.x;
    if (g < NA_T) {
        int i = (int)(g / 320), k = (int)(g % 320);
        float v = (k < E_) ? emb[(long)words[i] * E_ + k] : 0.f;
        Abf[g] = f32_to_bf16(v);
        return;
    }
    g -= NA_T;
    if (g < NB_T) {
        int r = (int)(g / 320), k = (int)(g % 320);
        float v = 0.f;
        if (r < NG_ && k < E_) v = (r < 800) ? wihf[r * E_ + k] : wihb[(r - 800) * E_ + k];
        Bbf[g] = f32_to_bf16(v);
        return;
    }
    g -= NB_T;
    if (g < 25600) {   // wtagB [64][400], rows >=50 zero
        int s = (int)(g / 400), k = (int)(g % 400);
        float v = (s < S_) ? wtag[s * H_ + k] : 0.f;
        wtagB[g] = f32_to_bf16(v);
        return;
    }
    g -= 25600;
    if (g < 1600) { biasC[g] = (g < 800) ? bfc[g] : bbc[g - 800]; return; }
}

// ---------------- w_hh quant: one WAVE per row. Global w8 layout (k-major chunks):
__global__ __launch_bounds__(256) void quant_kernel(const float* __restrict__ whh_f,
                                                    const float* __restrict__ whh_b,
                                                    signed char* __restrict__ w8,
                                                    float* __restrict__ invs) {
    int gw = (int)((blockIdx.x * 256 + threadIdx.x) >> 6);
    int lane = threadIdx.x & 63;
    if (gw >= 1600) return;
    int dir = gw / 800, row = gw % 800;
    const float* w = (dir ? whh_b : whh_f) + row * HD_;
    float m = 1e-20f;
    for (int k = lane; k < HD_; k += 64) m = fmaxf(m, fabsf(w[k]));
    for (int off = 32; off; off >>= 1) m = fmaxf(m, __shfl_xor(m, off));
    float s = 127.f / m;
    if (lane < 50) {
        int k0 = lane * 4;
        unsigned pk = 0;
#pragma unroll
        for (int i = 0; i < 4; ++i) {
            int v = (int)rintf(w[k0 + i] * s);
            pk |= ((unsigned)(v & 0xff)) << (8 * i);
        }
        unsigned char* base = (unsigned char*)w8 + dir * 160000;
        if (lane < 48) {
            int j = lane >> 2, wsel = lane & 3;
            *(unsigned*)(base + (size_t)(j * 800 + row) * 16 + wsel * 4) = pk;
        } else {
            *(unsigned*)(base + 153600 + (size_t)row * 8 + (lane - 48) * 4) = pk;
        }
    }
    if (lane == 0) invs[gw] = m / 16129.f;   // m/(127*127)
}

// ---------------- xg GEMM (MFMA bf16), staged from pre-converted bf16 A'/B'. (unchanged)
__global__ __launch_bounds__(256) void xg_gemm(const unsigned short* __restrict__ Abf,
                                               const unsigned short* __restrict__ Bbf,
                                               const float* __restrict__ biasC,
                                               unsigned short* __restrict__ xg) {
    __shared__ unsigned short As[128 * 40];
    __shared__ unsigned short Bs[128 * 40];
    int tid = threadIdx.x;
    int bm = blockIdx.y * 128;
    int bn = blockIdx.x * 128;
    int srow = tid >> 1, half = tid & 1;
    int lane = tid & 63, wave = tid >> 6, r16 = lane & 15, kh = lane >> 4;

    f32x4 acc[2][8];
#pragma unroll
    for (int mi = 0; mi < 2; ++mi)
#pragma unroll
        for (int ni = 0; ni < 8; ++ni) acc[mi][ni] = (f32x4){0.f, 0.f, 0.f, 0.f};

    const unsigned short* Ar = Abf + (long)(bm + srow) * 320;
    const unsigned short* Br = Bbf + (long)(bn + srow) * 320;

    for (int k0 = 0; k0 < 320; k0 += 32) {
#pragma unroll
        for (int j = 0; j < 2; ++j) {
            int off = half * 16 + j * 8;
            *(uint4*)&As[srow * 40 + off] = *(const uint4*)(Ar + k0 + off);
            *(uint4*)&Bs[srow * 40 + off] = *(const uint4*)(Br + k0 + off);
        }
        __syncthreads();
        short8 af[2], bfv[8];
#pragma unroll
        for (int mi = 0; mi < 2; ++mi)
            af[mi] = *(const short8*)&As[(wave * 32 + mi * 16 + r16) * 40 + kh * 8];
#pragma unroll
        for (int ni = 0; ni < 8; ++ni)
            bfv[ni] = *(const short8*)&Bs[(ni * 16 + r16) * 40 + kh * 8];
#pragma unroll
        for (int mi = 0; mi < 2; ++mi)
#pragma unroll
            for (int ni = 0; ni < 8; ++ni)
                acc[mi][ni] = __builtin_amdgcn_mfma_f32_16x16x32_bf16(af[mi], bfv[ni], acc[mi][ni], 0, 0, 0);
        __syncthreads();
    }
#pragma unroll
    for (int ni = 0; ni < 8; ++ni) {
        int g = bn + ni * 16 + r16;
        if (g < NG_) {
            float bias = biasC[g];
#pragma unroll
            for (int mi = 0; mi < 2; ++mi) {
#pragma unroll
                for (int r = 0; r < 4; ++r) {
                    int row = bm + wave * 32 + mi * 16 + kh * 4 + r;
                    xg[(long)row * NG_ + g] = f32_to_bf16(acc[mi][ni][r] + bias);
                }
            }
        }
    }
}

// ---------------- LSTM recurrence: unchanged from R17 (int8 weights ~register-resident).
__global__ __launch_bounds__(832) void lstm_rec(const unsigned short* __restrict__ xg,
                                                const signed char* __restrict__ w8,
                                                const float* __restrict__ invs,
                                                unsigned short* __restrict__ lstm16) {
    __shared__ __align__(16) unsigned char hbuf[256];   // int8 h (200 used)
    __shared__ float a_lds[800];                        // gate activations [q*200+ko]
    int tid = threadIdx.x;
    int dir = blockIdx.x >> 6;
    int b = blockIdx.x & 63;
    bool act = tid < 800;
    int tw = act ? tid : 0;
    int q = tid / 200;   // 0=i 1=f 2=g 3=o

    const unsigned char* wbase = (const unsigned char*)w8 + dir * 160000;
    uint4 wA[12];
    uint2 wAt;
#pragma unroll
    for (int j = 0; j < 12; ++j)
        wA[j] = *(const uint4*)(wbase + (size_t)(j * 800 + tw) * 16);
    wAt = *(const uint2*)(wbase + 153600 + (size_t)tw * 8);
#pragma unroll
    for (int j = 0; j < 12; ++j)
        asm volatile("" : "+v"(wA[j].x), "+v"(wA[j].y), "+v"(wA[j].z), "+v"(wA[j].w));
    asm volatile("" : "+v"(wAt.x), "+v"(wAt.y));

    float invsc = act ? invs[dir * 800 + tid] : 0.f;
    if (tid < 64) ((unsigned*)hbuf)[tid] = 0u;   // h=0
    float c = 0.f;
    __syncthreads();

    const uint4* h4c = (const uint4*)hbuf;
    const uint2* ht2 = (const uint2*)(hbuf + 192);
    const unsigned short* xbase = xg + (long)b * L_ * NG_ + dir * 800;

    int t0 = dir ? (L_ - 1) : 0;
    float x = act ? bf16_to_f32(xbase[(long)t0 * NG_ + tid]) : 0.f;

    for (int step = 0; step < L_; ++step) {
        int t = dir ? (L_ - 1 - step) : step;
        float x_n = 0.f;
        if (act && step + 1 < L_) {
            int tn = dir ? (t - 1) : (t + 1);
            x_n = bf16_to_f32(xbase[(long)tn * NG_ + tid]);
        }
        if (act) {
            int di = 0;
#pragma unroll
            for (int j = 0; j < 12; ++j) {
                uint4 hh = h4c[j];
                di = dot4(wA[j].x, hh.x, di); di = dot4(wA[j].y, hh.y, di);
                di = dot4(wA[j].z, hh.z, di); di = dot4(wA[j].w, hh.w, di);
            }
            {
                uint2 hh = ht2[0];
                di = dot4(wAt.x, hh.x, di); di = dot4(wAt.y, hh.y, di);
            }
            float p = x + (float)di * invsc;
            float av;
            if (q == 2) {
                float e = __expf(-2.f * p);          // tanh(g)
                av = 2.f / (1.f + e) - 1.f;
            } else {
                av = 1.f / (1.f + __expf(-p));       // sigmoid (i,f,o)
            }
            a_lds[tid] = av;
        }
        __syncthreads();
        if (tid < HD_) {
            float ig = a_lds[tid];
            float fg = a_lds[200 + tid];
            float gg = a_lds[400 + tid];
            float og = a_lds[600 + tid];
            c = fg * c + ig * gg;
            float ec = __expf(-2.f * c);
            float hn = og * (2.f / (1.f + ec) - 1.f);
            ((signed char*)hbuf)[tid] = (signed char)(int)rintf(hn * 127.f);
            lstm16[((long)(b * L_ + t)) * H_ + dir * HD_ + tid] = f32_to_bf16(hn);
        }
        x = x_n;
        __syncthreads();
    }
}

// ---------------- features via MFMA (unchanged)
__global__ __launch_bounds__(256) void feat_kernel(const unsigned short* __restrict__ lstm16,
                                                   const unsigned short* __restrict__ wtagB,
                                                   const float* __restrict__ btag,
                                                   float* __restrict__ feats) {
    __shared__ unsigned short As[128 * 40];
    __shared__ unsigned short Bs[64 * 40];
    int tid = threadIdx.x;
    int bm = blockIdx.x * 128;
    int srow = tid >> 1, half = tid & 1;
    int lane = tid & 63, wave = tid >> 6, r16 = lane & 15, kh = lane >> 4;

    f32x4 acc[2][4];
#pragma unroll
    for (int mi = 0; mi < 2; ++mi)
#pragma unroll
        for (int ni = 0; ni < 4; ++ni) acc[mi][ni] = (f32x4){0.f, 0.f, 0.f, 0.f};

    const unsigned short* Ar = lstm16 + (long)(bm + srow) * 400;
    const unsigned short* Br = wtagB + (long)srow * 400;

    for (int k0 = 0; k0 < 400; k0 += 32) {
#pragma unroll
        for (int j = 0; j < 2; ++j) {
            int off = half * 16 + j * 8;
            bool kv = (k0 + off + 8 <= 400);
            uint4 z = make_uint4(0u, 0u, 0u, 0u);
            *(uint4*)&As[srow * 40 + off] = kv ? *(const uint4*)(Ar + k0 + off) : z;
            if (srow < 64)
                *(uint4*)&Bs[srow * 40 + off] = kv ? *(const uint4*)(Br + k0 + off) : z;
        }
        __syncthreads();
        short8 af[2], bfv[4];
#pragma unroll
        for (int mi = 0; mi < 2; ++mi)
            af[mi] = *(const short8*)&As[(wave * 32 + mi * 16 + r16) * 40 + kh * 8];
#pragma unroll
        for (int ni = 0; ni < 4; ++ni)
            bfv[ni] = *(const short8*)&Bs[(ni * 16 + r16) * 40 + kh * 8];
#pragma unroll
        for (int mi = 0; mi < 2; ++mi)
#pragma unroll
            for (int ni = 0; ni < 4; ++ni)
                acc[mi][ni] = __builtin_amdgcn_mfma_f32_16x16x32_bf16(af[mi], bfv[ni], acc[mi][ni], 0, 0, 0);
        __syncthreads();
    }
#pragma unroll
    for (int ni = 0; ni < 4; ++ni) {
        int g = ni * 16 + r16;
        if (g < S_) {
            float bias = btag[g];
#pragma unroll
            for (int mi = 0; mi < 2; ++mi) {
#pragma unroll
                for (int r = 0; r < 4; ++r) {
                    int row = bm + wave * 32 + mi * 16 + kh * 4 + r;
                    feats[(long)row * S_ + g] = acc[mi][ni][r] + bias;
                }
            }
        }
    }
}

// ---------------- CRF: ONE WAVE per batch, wave-synchronous (R17 counters: old version
// was barrier+bank-conflict bound — 8 waves x 2 barriers x 128 steps, 1.17M conflicts,
// VALU 9.5%). Now: j=lane, alpha in lane j's REGISTER, LSE over i via v_readlane
// broadcast (VALU, no LDS) + transposed T in LDS with stride 53 (odd -> 53*j mod 32
// bijective -> conflict-free). Zero barriers in the 128-step loop.
__global__ __launch_bounds__(64) void crf_kernel(const float* __restrict__ feats,
                                                 const float* __restrict__ trans,
                                                 const int* __restrict__ tags,
                                                 const int* __restrict__ seqlens,
                                                 float* __restrict__ part) {
    __shared__ float Tt[S_ * 53];   // Tt[j*53+i] = trans[i*50+j] = T[i][j]
    __shared__ int tg[L_];
    int lane = threadIdx.x;
    int b = blockIdx.x;
    for (int idx = lane; idx < S_ * S_; idx += 64) {
        int j = idx / S_, i = idx % S_;
        Tt[j * 53 + i] = trans[i * S_ + j];
    }
    for (int idx = lane; idx < L_; idx += 64) tg[idx] = tags[b * L_ + idx];
    int slen = seqlens[b];
    const float* fb = feats + (long)b * L_ * S_;
    __syncthreads();

    bool act = lane < S_;
    const float* Trow = Tt + (act ? lane : 0) * 53;
    float alpha = act ? (Trow[START_] + fb[lane]) : -1e30f;
    float lal = alpha;   // valid if slen==1

    for (int t = 1; t < L_; ++t) {
        const float* fbt = fb + t * S_;
        float fval = act ? fbt[lane] : 0.f;
        // pass 1: max over i (2 chains to shorten dependency)
        float m0 = -1e30f, m1 = -1e30f;
#pragma unroll
        for (int i = 0; i < S_; i += 2) {
            m0 = fmaxf(m0, rlanef(alpha, i) + Trow[i]);
            m1 = fmaxf(m1, rlanef(alpha, i + 1) + Trow[i + 1]);
        }
        float m = fmaxf(m0, m1);
        // pass 2: exp-sum (4 accumulators)
        float s0 = 0.f, s1 = 0.f, s2 = 0.f, s3 = 0.f;
#pragma unroll
        for (int i = 0; i < S_; i += 4) {
            s0 += __expf(rlanef(alpha, i) + Trow[i] - m);
            s1 += __expf(rlanef(alpha, i + 1) + Trow[i + 1] - m);
            s2 += __expf(rlanef(alpha, i + 2) + Trow[i + 2] - m);
            s3 += __expf(rlanef(alpha, i + 3) + Trow[i + 3] - m);
        }
        float anew = m + __logf((s0 + s1) + (s2 + s3)) + fval;
        alpha = act ? anew : -1e30f;
        if (t == slen - 1) lal = alpha;
    }

    // unlabeled: LSE over j of (lal + T[j][END]);  T[j][END_] = Tt[END_*53 + j]
    float la = act ? (lal + Tt[END_ * 53 + lane]) : -1e30f;
    float m = la;
    for (int off = 32; off; off >>= 1) m = fmaxf(m, __shfl_xor(m, off));
    float e = act ? __expf(la - m) : 0.f;
    for (int off = 32; off; off >>= 1) e += __shfl_xor(e, off);
    float unl = m + __logf(e);

    // labeled path:  T[i][j] = Tt[j*53+i]
    float lab = 0.f;
    for (int tt = lane; tt < L_; tt += 64) {
        if (tt == 0) {
            lab += Tt[tg[0] * 53 + START_] + fb[tg[0]];
        } else if (tt < slen) {
            lab += Tt[tg[tt] * 53 + tg[tt - 1]] + fb[tt * S_ + tg[tt]];
        }
    }
    if (lane == 0) lab += Tt[END_ * 53 + tg[slen - 1]];
    for (int off = 32; off; off >>= 1) lab += __shfl_xor(lab, off);
    if (lane == 0) part[b] = unl - lab;
}

// ---------------- final: deterministic fixed-order sum of 64 partials
__global__ void fin_kernel(const float* __restrict__ part, float* __restrict__ out) {
    float s = 0.f;
    for (int i = 0; i < B_; ++i) s += part[i];
    out[0] = s;
}

extern "C" void kernel_launch(void* const* d_in, const int* in_sizes, int n_in,
                              void* d_out, int out_size, void* d_ws, size_t ws_size,
                              hipStream_t stream) {
    const int*   words = (const int*)d_in[0];
    const int*   slens = (const int*)d_in[1];
    // d_in[2] = masks: semantically (t < seq_len); not read.
    const int*   tags  = (const int*)d_in[3];
    const float* emb   = (const float*)d_in[4];
    const float* wihf  = (const float*)d_in[5];
    const float* whhf  = (const float*)d_in[6];
    const float* bf    = (const float*)d_in[7];
    const float* wihb  = (const float*)d_in[8];
    const float* whhb  = (const float*)d_in[9];
    const float* bb    = (const float*)d_in[10];
    const float* wtag  = (const float*)d_in[11];
    const float* btag  = (const float*)d_in[12];
    const float* trans = (const float*)d_in[13];

    char* ws = (char*)d_ws;
    unsigned short* xg     = (unsigned short*)(ws + OFF_XG);
    unsigned short* lstm16 = (unsigned short*)(ws + OFF_LSTM);
    unsigned short* Abf    = (unsigned short*)(ws + OFF_ABF);  // prep -> xg (overlaid by lstm16)
    unsigned short* Bbf    = (unsigned short*)(ws + OFF_BBF);  // prep -> xg (overlaid by lstm16)
    signed char*    w8     = (signed char*)(ws + OFF_SH);      // quant -> lstm
    float*          fts    = (float*)(ws + OFF_SH);            // feat -> crf (time-shared with w8)
    float*          invs   = (float*)(ws + OFF_INV);
    unsigned short* wtagB  = (unsigned short*)(ws + OFF_WTB);
    float*          biaC   = (float*)(ws + OFF_BIA);
    float*          part   = (float*)(ws + OFF_PART);
    float*          out    = (float*)d_out;

    prep_kernel<<<PREP_BLOCKS, 256, 0, stream>>>(words, emb, wihf, wihb, bf, bb,
                                                 wtag, Abf, Bbf, wtagB, biaC);
    quant_kernel<<<400, 256, 0, stream>>>(whhf, whhb, w8, invs);
    xg_gemm<<<dim3(13, 64), 256, 0, stream>>>(Abf, Bbf, biaC, xg);
    lstm_rec<<<128, 832, 0, stream>>>(xg, w8, invs, lstm16);
    feat_kernel<<<64, 256, 0, stream>>>(lstm16, wtagB, btag, fts);
    crf_kernel<<<64, 64, 0, stream>>>(fts, trans, tags, slens, part);
    fin_kernel<<<1, 1, 0, stream>>>(part, out);
}

// Round 19
// 279.530 us; speedup vs baseline: 1.6367x; 1.1259x over previous
//
#include <hip/hip_runtime.h>
#include <hip/hip_fp16.h>

#define B_ 64
#define L_ 128
#define E_ 300
#define HD_ 200
#define H_ 400
#define S_ 50
#define START_ 48
#define END_ 49
#define NG_ 1600
#define BL_ 8192

// ---- ws layout (bytes) ----
#define OFF_XG   0ull                          // bf16 [8192][1600]  26,214,400
#define OFF_LSTM 26214400ull                   // bf16 [8192][400]  6,553,600 (lstm16; overlays A'/B')
#define OFF_ABF  OFF_LSTM                      // bf16 [8192][320]    5,242,880 (prep->xg)
#define OFF_BBF  (OFF_LSTM + 5242880ull)       // bf16 [1664][320]    1,064,960 (prep->xg)
#define OFF_SH   (OFF_LSTM + 13107200ull)      // max(w8 320,000 ; feats 1,638,400)
#define OFF_INV  (OFF_SH + 1638400ull)         // f32 [1600]  6,400
#define OFF_WTB  (OFF_INV + 6400ull)           // bf16 [64][400] 51,200 (wtagB)
#define OFF_BIA  (OFF_WTB + 80000ull)          // f32 [1600]  6,400
#define OFF_PART (OFF_BIA + 6400ull)           // f32 [64] per-batch partials

#define NA_T 2621440   // 8192*320
#define NB_T 532480    // 1664*320
// prep items = NA_T + NB_T + 25600 (wtagB) + 1600 (biasC) = 3,181,120
// grid 12427*256 = 3,181,312 >= 3,181,120
#define PREP_BLOCKS 12427

typedef __attribute__((ext_vector_type(8))) short short8;
typedef __attribute__((ext_vector_type(4))) float f32x4;

__device__ __forceinline__ unsigned short f32_to_bf16(float f) {
    unsigned u = __float_as_uint(f);
    unsigned r = u + 0x7fffu + ((u >> 16) & 1u);
    return (unsigned short)(r >> 16);
}
__device__ __forceinline__ float bf16_to_f32(unsigned short s) {
    return __uint_as_float(((unsigned)s) << 16);
}
// 4-wide int8 dot with i32 accumulate: v_dot4_i32_i8 (fallback: manual sext).
__device__ __forceinline__ int dot4(unsigned a, unsigned b, int c) {
#if __has_builtin(__builtin_amdgcn_sdot4)
    return __builtin_amdgcn_sdot4(a, b, c, false);
#else
    c += (int)(signed char)(a)       * (int)(signed char)(b);
    c += (int)(signed char)(a >> 8)  * (int)(signed char)(b >> 8);
    c += (int)(signed char)(a >> 16) * (int)(signed char)(b >> 16);
    c += (int)(signed char)(a >> 24) * (int)(signed char)(b >> 24);
    return c;
#endif
}
// wave-uniform broadcast of lane l's value (VALU readlane; fallback shfl)
__device__ __forceinline__ float rlanef(float v, int l) {
#if __has_builtin(__builtin_amdgcn_readlane)
    return __uint_as_float(__builtin_amdgcn_readlane(__float_as_uint(v), l));
#else
    return __shfl(v, l, 64);
#endif
}

// ---------------- prep: A' gather->bf16(pad 320), B' weights->bf16, wtagB bf16[64][400], biasC.
__global__ void prep_kernel(const int* __restrict__ words, const float* __restrict__ emb,
                            const float* __restrict__ wihf, const float* __restrict__ wihb,
                            const float* __restrict__ bfc, const float* __restrict__ bbc,
                            const float* __restrict__ wtag,
                            unsigned short* __restrict__ Abf, unsigned short* __restrict__ Bbf,
                            unsigned short* __restrict__ wtagB, float* __restrict__ biasC) {
    long g = (long)blockIdx.x * 256 + threadIdx.x;
    if (g < NA_T) {
        int i = (int)(g / 320), k = (int)(g % 320);
        float v = (k < E_) ? emb[(long)words[i] * E_ + k] : 0.f;
        Abf[g] = f32_to_bf16(v);
        return;
    }
    g -= NA_T;
    if (g < NB_T) {
        int r = (int)(g / 320), k = (int)(g % 320);
        float v = 0.f;
        if (r < NG_ && k < E_) v = (r < 800) ? wihf[r * E_ + k] : wihb[(r - 800) * E_ + k];
        Bbf[g] = f32_to_bf16(v);
        return;
    }
    g -= NB_T;
    if (g < 25600) {   // wtagB [64][400], rows >=50 zero
        int s = (int)(g / 400), k = (int)(g % 400);
        float v = (s < S_) ? wtag[s * H_ + k] : 0.f;
        wtagB[g] = f32_to_bf16(v);
        return;
    }
    g -= 25600;
    if (g < 1600) { biasC[g] = (g < 800) ? bfc[g] : bbc[g - 800]; return; }
}

// ---------------- w_hh quant: one WAVE per row. Global w8 layout (k-major chunks):
//   [dir] { chunks [j=0..11][row 0..799] uint4 at (j*800+row)*16 ; tails [row] uint2 at 153600+row*8 }
__global__ __launch_bounds__(256) void quant_kernel(const float* __restrict__ whh_f,
                                                    const float* __restrict__ whh_b,
                                                    signed char* __restrict__ w8,
                                                    float* __restrict__ invs) {
    int gw = (int)((blockIdx.x * 256 + threadIdx.x) >> 6);
    int lane = threadIdx.x & 63;
    if (gw >= 1600) return;
    int dir = gw / 800, row = gw % 800;
    const float* w = (dir ? whh_b : whh_f) + row * HD_;
    float m = 1e-20f;
    for (int k = lane; k < HD_; k += 64) m = fmaxf(m, fabsf(w[k]));
    for (int off = 32; off; off >>= 1) m = fmaxf(m, __shfl_xor(m, off));
    float s = 127.f / m;
    if (lane < 50) {
        int k0 = lane * 4;
        unsigned pk = 0;
#pragma unroll
        for (int i = 0; i < 4; ++i) {
            int v = (int)rintf(w[k0 + i] * s);
            pk |= ((unsigned)(v & 0xff)) << (8 * i);
        }
        unsigned char* base = (unsigned char*)w8 + dir * 160000;
        if (lane < 48) {
            int j = lane >> 2, wsel = lane & 3;
            *(unsigned*)(base + (size_t)(j * 800 + row) * 16 + wsel * 4) = pk;
        } else {
            *(unsigned*)(base + 153600 + (size_t)row * 8 + (lane - 48) * 4) = pk;
        }
    }
    if (lane == 0) invs[gw] = m / 16129.f;   // m/(127*127)
}

// ---------------- xg GEMM (MFMA bf16), staged from pre-converted bf16 A'/B'. (unchanged)
__global__ __launch_bounds__(256) void xg_gemm(const unsigned short* __restrict__ Abf,
                                               const unsigned short* __restrict__ Bbf,
                                               const float* __restrict__ biasC,
                                               unsigned short* __restrict__ xg) {
    __shared__ unsigned short As[128 * 40];
    __shared__ unsigned short Bs[128 * 40];
    int tid = threadIdx.x;
    int bm = blockIdx.y * 128;
    int bn = blockIdx.x * 128;
    int srow = tid >> 1, half = tid & 1;
    int lane = tid & 63, wave = tid >> 6, r16 = lane & 15, kh = lane >> 4;

    f32x4 acc[2][8];
#pragma unroll
    for (int mi = 0; mi < 2; ++mi)
#pragma unroll
        for (int ni = 0; ni < 8; ++ni) acc[mi][ni] = (f32x4){0.f, 0.f, 0.f, 0.f};

    const unsigned short* Ar = Abf + (long)(bm + srow) * 320;
    const unsigned short* Br = Bbf + (long)(bn + srow) * 320;

    for (int k0 = 0; k0 < 320; k0 += 32) {
#pragma unroll
        for (int j = 0; j < 2; ++j) {
            int off = half * 16 + j * 8;
            *(uint4*)&As[srow * 40 + off] = *(const uint4*)(Ar + k0 + off);
            *(uint4*)&Bs[srow * 40 + off] = *(const uint4*)(Br + k0 + off);
        }
        __syncthreads();
        short8 af[2], bfv[8];
#pragma unroll
        for (int mi = 0; mi < 2; ++mi)
            af[mi] = *(const short8*)&As[(wave * 32 + mi * 16 + r16) * 40 + kh * 8];
#pragma unroll
        for (int ni = 0; ni < 8; ++ni)
            bfv[ni] = *(const short8*)&Bs[(ni * 16 + r16) * 40 + kh * 8];
#pragma unroll
        for (int mi = 0; mi < 2; ++mi)
#pragma unroll
            for (int ni = 0; ni < 8; ++ni)
                acc[mi][ni] = __builtin_amdgcn_mfma_f32_16x16x32_bf16(af[mi], bfv[ni], acc[mi][ni], 0, 0, 0);
        __syncthreads();
    }
#pragma unroll
    for (int ni = 0; ni < 8; ++ni) {
        int g = bn + ni * 16 + r16;
        if (g < NG_) {
            float bias = biasC[g];
#pragma unroll
            for (int mi = 0; mi < 2; ++mi) {
#pragma unroll
                for (int r = 0; r < 4; ++r) {
                    int row = bm + wave * 32 + mi * 16 + kh * 4 + r;
                    xg[(long)row * NG_ + g] = f32_to_bf16(acc[mi][ni][r] + bias);
                }
            }
        }
    }
}

// ---------------- LSTM recurrence: two-pipe v2 at 13 waves.
// R17/18 (spill-stream all 200B/row) = per-CU L2-BW bound at ~139 GB/s -> 147us.
// Now: chunks 0..5 (96B/row, 76.8KB) LDS-RESIDENT; chunks 6..11+tail (104B/row,
// 83.2KB/step) explicitly streamed — addresses are step-invariant and issued at loop
// top, so their ~500cyc latency hides under the LDS-chunk dots. Unlike R15 (8 waves,
// 2 rows/thr, latency-bound), this keeps 832thr/13 waves/1 row. Streams ~1490cyc,
// LDS ~1280cyc, overlapped -> ~1500cyc/step (vs 2460).
__global__ __launch_bounds__(832) void lstm_rec(const unsigned short* __restrict__ xg,
                                                const signed char* __restrict__ w8,
                                                const float* __restrict__ invs,
                                                unsigned short* __restrict__ lstm16) {
    __shared__ __align__(16) uint4 wlds[4800];          // chunks 0..5: [j][800] 76,800 B
    __shared__ __align__(16) unsigned char hbuf[256];   // int8 h (200 used)
    __shared__ float a_lds[800];                        // gate activations [q*200+ko]
    int tid = threadIdx.x;
    int dir = blockIdx.x >> 6;
    int b = blockIdx.x & 63;
    bool act = tid < 800;
    int tw = act ? tid : 0;
    int q = tid / 200;   // 0=i 1=f 2=g 3=o

    const unsigned char* wbase = (const unsigned char*)w8 + dir * 160000;
    {   // stage chunks 0..5 (first 76,800 B, layout-identical) into LDS
        const uint4* src = (const uint4*)wbase;
        for (int i = tid; i < 4800; i += 832) wlds[i] = src[i];
    }
    const uint4* wstr = (const uint4*)wbase + 6 * 800 + tw;          // chunks 6..11
    const uint2* wtsr = (const uint2*)(wbase + 153600) + tw;         // tail

    float invsc = act ? invs[dir * 800 + tid] : 0.f;
    if (tid < 64) ((unsigned*)hbuf)[tid] = 0u;   // h=0
    float c = 0.f;
    __syncthreads();

    const uint4* h4c = (const uint4*)hbuf;
    const uint2* ht2 = (const uint2*)(hbuf + 192);
    const unsigned short* xbase = xg + (long)b * L_ * NG_ + dir * 800;

    int t0 = dir ? (L_ - 1) : 0;
    float x = act ? bf16_to_f32(xbase[(long)t0 * NG_ + tid]) : 0.f;

    for (int step = 0; step < L_; ++step) {
        int t = dir ? (L_ - 1 - step) : step;
        // issue streamed weight loads FIRST (step-invariant; in flight during LDS dots)
        uint4 w6 = wstr[0], w7 = wstr[800], w8r = wstr[1600];
        uint4 w9 = wstr[2400], w10 = wstr[3200], w11 = wstr[4000];
        uint2 wt = wtsr[0];
        float x_n = 0.f;
        if (act && step + 1 < L_) {
            int tn = dir ? (t - 1) : (t + 1);
            x_n = bf16_to_f32(xbase[(long)tn * NG_ + tid]);
        }
        if (act) {
            int di = 0;
#pragma unroll
            for (int j = 0; j < 6; ++j) {            // LDS-resident chunks
                uint4 wv = wlds[j * 800 + tw];
                uint4 hh = h4c[j];
                di = dot4(wv.x, hh.x, di); di = dot4(wv.y, hh.y, di);
                di = dot4(wv.z, hh.z, di); di = dot4(wv.w, hh.w, di);
            }
            {   // streamed chunks 6..11
                uint4 hh;
                hh = h4c[6];  di = dot4(w6.x, hh.x, di);  di = dot4(w6.y, hh.y, di);
                              di = dot4(w6.z, hh.z, di);  di = dot4(w6.w, hh.w, di);
                hh = h4c[7];  di = dot4(w7.x, hh.x, di);  di = dot4(w7.y, hh.y, di);
                              di = dot4(w7.z, hh.z, di);  di = dot4(w7.w, hh.w, di);
                hh = h4c[8];  di = dot4(w8r.x, hh.x, di); di = dot4(w8r.y, hh.y, di);
                              di = dot4(w8r.z, hh.z, di); di = dot4(w8r.w, hh.w, di);
                hh = h4c[9];  di = dot4(w9.x, hh.x, di);  di = dot4(w9.y, hh.y, di);
                              di = dot4(w9.z, hh.z, di);  di = dot4(w9.w, hh.w, di);
                hh = h4c[10]; di = dot4(w10.x, hh.x, di); di = dot4(w10.y, hh.y, di);
                              di = dot4(w10.z, hh.z, di); di = dot4(w10.w, hh.w, di);
                hh = h4c[11]; di = dot4(w11.x, hh.x, di); di = dot4(w11.y, hh.y, di);
                              di = dot4(w11.z, hh.z, di); di = dot4(w11.w, hh.w, di);
                uint2 h2 = ht2[0];
                di = dot4(wt.x, h2.x, di); di = dot4(wt.y, h2.y, di);
            }
            float p = x + (float)di * invsc;
            float av;
            if (q == 2) {
                float e = __expf(-2.f * p);          // tanh(g)
                av = 2.f / (1.f + e) - 1.f;
            } else {
                av = 1.f / (1.f + __expf(-p));       // sigmoid (i,f,o)
            }
            a_lds[tid] = av;
        }
        __syncthreads();
        if (tid < HD_) {
            float ig = a_lds[tid];
            float fg = a_lds[200 + tid];
            float gg = a_lds[400 + tid];
            float og = a_lds[600 + tid];
            c = fg * c + ig * gg;
            float ec = __expf(-2.f * c);
            float hn = og * (2.f / (1.f + ec) - 1.f);
            ((signed char*)hbuf)[tid] = (signed char)(int)rintf(hn * 127.f);
            lstm16[((long)(b * L_ + t)) * H_ + dir * HD_ + tid] = f32_to_bf16(hn);
        }
        x = x_n;
        __syncthreads();
    }
}

// ---------------- features via MFMA (unchanged)
__global__ __launch_bounds__(256) void feat_kernel(const unsigned short* __restrict__ lstm16,
                                                   const unsigned short* __restrict__ wtagB,
                                                   const float* __restrict__ btag,
                                                   float* __restrict__ feats) {
    __shared__ unsigned short As[128 * 40];
    __shared__ unsigned short Bs[64 * 40];
    int tid = threadIdx.x;
    int bm = blockIdx.x * 128;
    int srow = tid >> 1, half = tid & 1;
    int lane = tid & 63, wave = tid >> 6, r16 = lane & 15, kh = lane >> 4;

    f32x4 acc[2][4];
#pragma unroll
    for (int mi = 0; mi < 2; ++mi)
#pragma unroll
        for (int ni = 0; ni < 4; ++ni) acc[mi][ni] = (f32x4){0.f, 0.f, 0.f, 0.f};

    const unsigned short* Ar = lstm16 + (long)(bm + srow) * 400;
    const unsigned short* Br = wtagB + (long)srow * 400;

    for (int k0 = 0; k0 < 400; k0 += 32) {
#pragma unroll
        for (int j = 0; j < 2; ++j) {
            int off = half * 16 + j * 8;
            bool kv = (k0 + off + 8 <= 400);
            uint4 z = make_uint4(0u, 0u, 0u, 0u);
            *(uint4*)&As[srow * 40 + off] = kv ? *(const uint4*)(Ar + k0 + off) : z;
            if (srow < 64)
                *(uint4*)&Bs[srow * 40 + off] = kv ? *(const uint4*)(Br + k0 + off) : z;
        }
        __syncthreads();
        short8 af[2], bfv[4];
#pragma unroll
        for (int mi = 0; mi < 2; ++mi)
            af[mi] = *(const short8*)&As[(wave * 32 + mi * 16 + r16) * 40 + kh * 8];
#pragma unroll
        for (int ni = 0; ni < 4; ++ni)
            bfv[ni] = *(const short8*)&Bs[(ni * 16 + r16) * 40 + kh * 8];
#pragma unroll
        for (int mi = 0; mi < 2; ++mi)
#pragma unroll
            for (int ni = 0; ni < 4; ++ni)
                acc[mi][ni] = __builtin_amdgcn_mfma_f32_16x16x32_bf16(af[mi], bfv[ni], acc[mi][ni], 0, 0, 0);
        __syncthreads();
    }
#pragma unroll
    for (int ni = 0; ni < 4; ++ni) {
        int g = ni * 16 + r16;
        if (g < S_) {
            float bias = btag[g];
#pragma unroll
            for (int mi = 0; mi < 2; ++mi) {
#pragma unroll
                for (int r = 0; r < 4; ++r) {
                    int row = bm + wave * 32 + mi * 16 + kh * 4 + r;
                    feats[(long)row * S_ + g] = acc[mi][ni][r] + bias;
                }
            }
        }
    }
}

// ---------------- CRF: one wave per batch, exp-FACTORIZED (R18 was exp-issue bound:
// 50 quarter-rate exps/lane/step = 800cyc). LSE factorization:
//   sum_i exp(a_i + T_ij - m) = sum_i exp(a_i - m) * expT[i][j]
// expT precomputed ONCE into 50 registers per lane -> per step: 1 exp + 1 log +
// 50 readlane + 50 FMA. -10000 transitions give expT=0 (exact); s floored at 1e-38
// (log -> m-87.5, contribution e^-87 ~ 0, same as reference's e^-10000).
__global__ __launch_bounds__(64) void crf_kernel(const float* __restrict__ feats,
                                                 const float* __restrict__ trans,
                                                 const int* __restrict__ tags,
                                                 const int* __restrict__ seqlens,
                                                 float* __restrict__ part) {
    __shared__ float Tt[S_ * 53];   // Tt[j*53+i] = trans[i*50+j] = T[i][j]
    __shared__ int tg[L_];
    int lane = threadIdx.x;
    int b = blockIdx.x;
    for (int idx = lane; idx < S_ * S_; idx += 64) {
        int j = idx / S_, i = idx % S_;
        Tt[j * 53 + i] = trans[i * S_ + j];
    }
    for (int idx = lane; idx < L_; idx += 64) tg[idx] = tags[b * L_ + idx];
    int slen = seqlens[b];
    const float* fb = feats + (long)b * L_ * S_;
    __syncthreads();

    bool act = lane < S_;
    const float* Trow = Tt + (act ? lane : 0) * 53;
    // preload exp(T[i][lane]) into 50 registers (one wave/block: VGPRs plentiful)
    float eT[S_];
#pragma unroll
    for (int i = 0; i < S_; ++i) eT[i] = __expf(Trow[i]);

    float alpha = act ? (Trow[START_] + fb[lane]) : -1e30f;
    float lal = alpha;   // valid if slen==1

    for (int t = 1; t < L_; ++t) {
        float fval = act ? fb[t * S_ + lane] : 0.f;
        // wave-wide max of alpha
        float m = alpha;
        for (int off = 32; off; off >>= 1) m = fmaxf(m, __shfl_xor(m, off));
        float p = __expf(alpha - m);       // inactive lanes: exp(-1e30-m)=0
        float s0 = 0.f, s1 = 0.f, s2 = 0.f, s3 = 0.f, s4 = 0.f;
#pragma unroll
        for (int i = 0; i < S_; i += 5) {
            s0 = fmaf(rlanef(p, i),     eT[i],     s0);
            s1 = fmaf(rlanef(p, i + 1), eT[i + 1], s1);
            s2 = fmaf(rlanef(p, i + 2), eT[i + 2], s2);
            s3 = fmaf(rlanef(p, i + 3), eT[i + 3], s3);
            s4 = fmaf(rlanef(p, i + 4), eT[i + 4], s4);
        }
        float s = fmaxf(((s0 + s1) + (s2 + s3)) + s4, 1e-38f);
        float anew = m + __logf(s) + fval;
        alpha = act ? anew : -1e30f;
        if (t == slen - 1) lal = alpha;
    }

    // unlabeled: LSE over j of (lal + T[j][END]);  T[j][END_] = Tt[END_*53 + j]
    float la = act ? (lal + Tt[END_ * 53 + lane]) : -1e30f;
    float m = la;
    for (int off = 32; off; off >>= 1) m = fmaxf(m, __shfl_xor(m, off));
    float e = act ? __expf(la - m) : 0.f;
    for (int off = 32; off; off >>= 1) e += __shfl_xor(e, off);
    float unl = m + __logf(e);

    // labeled path:  T[i][j] = Tt[j*53+i]
    float lab = 0.f;
    for (int tt = lane; tt < L_; tt += 64) {
        if (tt == 0) {
            lab += Tt[tg[0] * 53 + START_] + fb[tg[0]];
        } else if (tt < slen) {
            lab += Tt[tg[tt] * 53 + tg[tt - 1]] + fb[tt * S_ + tg[tt]];
        }
    }
    if (lane == 0) lab += Tt[END_ * 53 + tg[slen - 1]];
    for (int off = 32; off; off >>= 1) lab += __shfl_xor(lab, off);
    if (lane == 0) part[b] = unl - lab;
}

// ---------------- final: deterministic fixed-order sum of 64 partials
__global__ void fin_kernel(const float* __restrict__ part, float* __restrict__ out) {
    float s = 0.f;
    for (int i = 0; i < B_; ++i) s += part[i];
    out[0] = s;
}

extern "C" void kernel_launch(void* const* d_in, const int* in_sizes, int n_in,
                              void* d_out, int out_size, void* d_ws, size_t ws_size,
                              hipStream_t stream) {
    const int*   words = (const int*)d_in[0];
    const int*   slens = (const int*)d_in[1];
    // d_in[2] = masks: semantically (t < seq_len); not read.
    const int*   tags  = (const int*)d_in[3];
    const float* emb   = (const float*)d_in[4];
    const float* wihf  = (const float*)d_in[5];
    const float* whhf  = (const float*)d_in[6];
    const float* bf    = (const float*)d_in[7];
    const float* wihb  = (const float*)d_in[8];
    const float* whhb  = (const float*)d_in[9];
    const float* bb    = (const float*)d_in[10];
    const float* wtag  = (const float*)d_in[11];
    const float* btag  = (const float*)d_in[12];
    const float* trans = (const float*)d_in[13];

    char* ws = (char*)d_ws;
    unsigned short* xg     = (unsigned short*)(ws + OFF_XG);
    unsigned short* lstm16 = (unsigned short*)(ws + OFF_LSTM);
    unsigned short* Abf    = (unsigned short*)(ws + OFF_ABF);  // prep -> xg (overlaid by lstm16)
    unsigned short* Bbf    = (unsigned short*)(ws + OFF_BBF);  // prep -> xg (overlaid by lstm16)
    signed char*    w8     = (signed char*)(ws + OFF_SH);      // quant -> lstm
    float*          fts    = (float*)(ws + OFF_SH);            // feat -> crf (time-shared with w8)
    float*          invs   = (float*)(ws + OFF_INV);
    unsigned short* wtagB  = (unsigned short*)(ws + OFF_WTB);
    float*          biaC   = (float*)(ws + OFF_BIA);
    float*          part   = (float*)(ws + OFF_PART);
    float*          out    = (float*)d_out;

    prep_kernel<<<PREP_BLOCKS, 256, 0, stream>>>(words, emb, wihf, wihb, bf, bb,
                                                 wtag, Abf, Bbf, wtagB, biaC);
    quant_kernel<<<400, 256, 0, stream>>>(whhf, whhb, w8, invs);
    xg_gemm<<<dim3(13, 64), 256, 0, stream>>>(Abf, Bbf, biaC, xg);
    lstm_rec<<<128, 832, 0, stream>>>(xg, w8, invs, lstm16);
    feat_kernel<<<64, 256, 0, stream>>>(lstm16, wtagB, btag, fts);
    crf_kernel<<<64, 64, 0, stream>>>(fts, trans, tags, slens, part);
    fin_kernel<<<1, 1, 0, stream>>>(part, out);
}

// Round 20
// 263.570 us; speedup vs baseline: 1.7358x; 1.0606x over previous
//
#include <hip/hip_runtime.h>
#include <hip/hip_fp16.h>

#define B_ 64
#define L_ 128
#define E_ 300
#define HD_ 200
#define H_ 400
#define S_ 50
#define START_ 48
#define END_ 49
#define NG_ 1600
#define BL_ 8192

// ---- ws layout (bytes) ----
#define OFF_XG   0ull                          // bf16 [8192][1600]  26,214,400
#define OFF_LSTM 26214400ull                   // bf16 [8192][400]  6,553,600 (lstm16; overlays A'/B')
#define OFF_ABF  OFF_LSTM                      // bf16 [8192][320]    5,242,880 (prep->xg)
#define OFF_BBF  (OFF_LSTM + 5242880ull)       // bf16 [1664][320]    1,064,960 (prep->xg)
#define OFF_SH   (OFF_LSTM + 13107200ull)      // max(w8 320,000 ; feats 1,638,400)
#define OFF_INV  (OFF_SH + 1638400ull)         // f32 [1600]  6,400
#define OFF_WTB  (OFF_INV + 6400ull)           // bf16 [64][400] 51,200 (wtagB)
#define OFF_BIA  (OFF_WTB + 80000ull)          // f32 [1600]  6,400
#define OFF_PART (OFF_BIA + 6400ull)           // f32 [64] per-batch partials

#define NA_T 2621440   // 8192*320
#define NB_T 532480    // 1664*320
// prep items = NA_T + NB_T + 25600 (wtagB) + 1600 (biasC) = 3,181,120
// grid 12427*256 = 3,181,312 >= 3,181,120
#define PREP_BLOCKS 12427

typedef __attribute__((ext_vector_type(8))) short short8;
typedef __attribute__((ext_vector_type(4))) float f32x4;

__device__ __forceinline__ unsigned short f32_to_bf16(float f) {
    unsigned u = __float_as_uint(f);
    unsigned r = u + 0x7fffu + ((u >> 16) & 1u);
    return (unsigned short)(r >> 16);
}
__device__ __forceinline__ float bf16_to_f32(unsigned short s) {
    return __uint_as_float(((unsigned)s) << 16);
}
// 4-wide int8 dot with i32 accumulate: v_dot4_i32_i8 (fallback: manual sext).
__device__ __forceinline__ int dot4(unsigned a, unsigned b, int c) {
#if __has_builtin(__builtin_amdgcn_sdot4)
    return __builtin_amdgcn_sdot4(a, b, c, false);
#else
    c += (int)(signed char)(a)       * (int)(signed char)(b);
    c += (int)(signed char)(a >> 8)  * (int)(signed char)(b >> 8);
    c += (int)(signed char)(a >> 16) * (int)(signed char)(b >> 16);
    c += (int)(signed char)(a >> 24) * (int)(signed char)(b >> 24);
    return c;
#endif
}
// wave-uniform broadcast of lane l's value (VALU readlane; fallback shfl)
__device__ __forceinline__ float rlanef(float v, int l) {
#if __has_builtin(__builtin_amdgcn_readlane)
    return __uint_as_float(__builtin_amdgcn_readlane(__float_as_uint(v), l));
#else
    return __shfl(v, l, 64);
#endif
}

// ---------------- prep: A' gather->bf16(pad 320), B' weights->bf16, wtagB bf16[64][400], biasC.
__global__ void prep_kernel(const int* __restrict__ words, const float* __restrict__ emb,
                            const float* __restrict__ wihf, const float* __restrict__ wihb,
                            const float* __restrict__ bfc, const float* __restrict__ bbc,
                            const float* __restrict__ wtag,
                            unsigned short* __restrict__ Abf, unsigned short* __restrict__ Bbf,
                            unsigned short* __restrict__ wtagB, float* __restrict__ biasC) {
    long g = (long)blockIdx.x * 256 + threadIdx.x;
    if (g < NA_T) {
        int i = (int)(g / 320), k = (int)(g % 320);
        float v = (k < E_) ? emb[(long)words[i] * E_ + k] : 0.f;
        Abf[g] = f32_to_bf16(v);
        return;
    }
    g -= NA_T;
    if (g < NB_T) {
        int r = (int)(g / 320), k = (int)(g % 320);
        float v = 0.f;
        if (r < NG_ && k < E_) v = (r < 800) ? wihf[r * E_ + k] : wihb[(r - 800) * E_ + k];
        Bbf[g] = f32_to_bf16(v);
        return;
    }
    g -= NB_T;
    if (g < 25600) {   // wtagB [64][400], rows >=50 zero
        int s = (int)(g / 400), k = (int)(g % 400);
        float v = (s < S_) ? wtag[s * H_ + k] : 0.f;
        wtagB[g] = f32_to_bf16(v);
        return;
    }
    g -= 25600;
    if (g < 1600) { biasC[g] = (g < 800) ? bfc[g] : bbc[g - 800]; return; }
}

// ---------------- w_hh quant: one WAVE per row. Global w8 layout (k-major chunks):
//   [dir] { chunks [j=0..11][row 0..799] uint4 at (j*800+row)*16 ; tails [row] uint2 at 153600+row*8 }
__global__ __launch_bounds__(256) void quant_kernel(const float* __restrict__ whh_f,
                                                    const float* __restrict__ whh_b,
                                                    signed char* __restrict__ w8,
                                                    float* __restrict__ invs) {
    int gw = (int)((blockIdx.x * 256 + threadIdx.x) >> 6);
    int lane = threadIdx.x & 63;
    if (gw >= 1600) return;
    int dir = gw / 800, row = gw % 800;
    const float* w = (dir ? whh_b : whh_f) + row * HD_;
    float m = 1e-20f;
    for (int k = lane; k < HD_; k += 64) m = fmaxf(m, fabsf(w[k]));
    for (int off = 32; off; off >>= 1) m = fmaxf(m, __shfl_xor(m, off));
    float s = 127.f / m;
    if (lane < 50) {
        int k0 = lane * 4;
        unsigned pk = 0;
#pragma unroll
        for (int i = 0; i < 4; ++i) {
            int v = (int)rintf(w[k0 + i] * s);
            pk |= ((unsigned)(v & 0xff)) << (8 * i);
        }
        unsigned char* base = (unsigned char*)w8 + dir * 160000;
        if (lane < 48) {
            int j = lane >> 2, wsel = lane & 3;
            *(unsigned*)(base + (size_t)(j * 800 + row) * 16 + wsel * 4) = pk;
        } else {
            *(unsigned*)(base + 153600 + (size_t)row * 8 + (lane - 48) * 4) = pk;
        }
    }
    if (lane == 0) invs[gw] = m / 16129.f;   // m/(127*127)
}

// ---------------- xg GEMM (MFMA bf16), staged from pre-converted bf16 A'/B'. (unchanged)
__global__ __launch_bounds__(256) void xg_gemm(const unsigned short* __restrict__ Abf,
                                               const unsigned short* __restrict__ Bbf,
                                               const float* __restrict__ biasC,
                                               unsigned short* __restrict__ xg) {
    __shared__ unsigned short As[128 * 40];
    __shared__ unsigned short Bs[128 * 40];
    int tid = threadIdx.x;
    int bm = blockIdx.y * 128;
    int bn = blockIdx.x * 128;
    int srow = tid >> 1, half = tid & 1;
    int lane = tid & 63, wave = tid >> 6, r16 = lane & 15, kh = lane >> 4;

    f32x4 acc[2][8];
#pragma unroll
    for (int mi = 0; mi < 2; ++mi)
#pragma unroll
        for (int ni = 0; ni < 8; ++ni) acc[mi][ni] = (f32x4){0.f, 0.f, 0.f, 0.f};

    const unsigned short* Ar = Abf + (long)(bm + srow) * 320;
    const unsigned short* Br = Bbf + (long)(bn + srow) * 320;

    for (int k0 = 0; k0 < 320; k0 += 32) {
#pragma unroll
        for (int j = 0; j < 2; ++j) {
            int off = half * 16 + j * 8;
            *(uint4*)&As[srow * 40 + off] = *(const uint4*)(Ar + k0 + off);
            *(uint4*)&Bs[srow * 40 + off] = *(const uint4*)(Br + k0 + off);
        }
        __syncthreads();
        short8 af[2], bfv[8];
#pragma unroll
        for (int mi = 0; mi < 2; ++mi)
            af[mi] = *(const short8*)&As[(wave * 32 + mi * 16 + r16) * 40 + kh * 8];
#pragma unroll
        for (int ni = 0; ni < 8; ++ni)
            bfv[ni] = *(const short8*)&Bs[(ni * 16 + r16) * 40 + kh * 8];
#pragma unroll
        for (int mi = 0; mi < 2; ++mi)
#pragma unroll
            for (int ni = 0; ni < 8; ++ni)
                acc[mi][ni] = __builtin_amdgcn_mfma_f32_16x16x32_bf16(af[mi], bfv[ni], acc[mi][ni], 0, 0, 0);
        __syncthreads();
    }
#pragma unroll
    for (int ni = 0; ni < 8; ++ni) {
        int g = bn + ni * 16 + r16;
        if (g < NG_) {
            float bias = biasC[g];
#pragma unroll
            for (int mi = 0; mi < 2; ++mi) {
#pragma unroll
                for (int r = 0; r < 4; ++r) {
                    int row = bm + wave * 32 + mi * 16 + kh * 4 + r;
                    xg[(long)row * NG_ + g] = f32_to_bf16(acc[mi][ni][r] + bias);
                }
            }
        }
    }
}

// ---------------- LSTM recurrence: EXACT R18 kernel (empirical best: 147 us; the
// allocator's spill-stream beats every hand-scheduled alternative tried:
// R18 147 < R19 hybrid 163 < R12 all-LDS 175 < R14 readlane 191 < R11 207 < R15 255).
__global__ __launch_bounds__(832) void lstm_rec(const unsigned short* __restrict__ xg,
                                                const signed char* __restrict__ w8,
                                                const float* __restrict__ invs,
                                                unsigned short* __restrict__ lstm16) {
    __shared__ __align__(16) unsigned char hbuf[256];   // int8 h (200 used)
    __shared__ float a_lds[800];                        // gate activations [q*200+ko]
    int tid = threadIdx.x;
    int dir = blockIdx.x >> 6;
    int b = blockIdx.x & 63;
    bool act = tid < 800;
    int tw = act ? tid : 0;
    int q = tid / 200;   // 0=i 1=f 2=g 3=o

    const unsigned char* wbase = (const unsigned char*)w8 + dir * 160000;
    uint4 wA[12];
    uint2 wAt;
#pragma unroll
    for (int j = 0; j < 12; ++j)
        wA[j] = *(const uint4*)(wbase + (size_t)(j * 800 + tw) * 16);
    wAt = *(const uint2*)(wbase + 153600 + (size_t)tw * 8);
#pragma unroll
    for (int j = 0; j < 12; ++j)
        asm volatile("" : "+v"(wA[j].x), "+v"(wA[j].y), "+v"(wA[j].z), "+v"(wA[j].w));
    asm volatile("" : "+v"(wAt.x), "+v"(wAt.y));

    float invsc = act ? invs[dir * 800 + tid] : 0.f;
    if (tid < 64) ((unsigned*)hbuf)[tid] = 0u;   // h=0
    float c = 0.f;
    __syncthreads();

    const uint4* h4c = (const uint4*)hbuf;
    const uint2* ht2 = (const uint2*)(hbuf + 192);
    const unsigned short* xbase = xg + (long)b * L_ * NG_ + dir * 800;

    int t0 = dir ? (L_ - 1) : 0;
    float x = act ? bf16_to_f32(xbase[(long)t0 * NG_ + tid]) : 0.f;

    for (int step = 0; step < L_; ++step) {
        int t = dir ? (L_ - 1 - step) : step;
        float x_n = 0.f;
        if (act && step + 1 < L_) {
            int tn = dir ? (t - 1) : (t + 1);
            x_n = bf16_to_f32(xbase[(long)tn * NG_ + tid]);
        }
        if (act) {
            int di = 0;
#pragma unroll
            for (int j = 0; j < 12; ++j) {
                uint4 hh = h4c[j];
                di = dot4(wA[j].x, hh.x, di); di = dot4(wA[j].y, hh.y, di);
                di = dot4(wA[j].z, hh.z, di); di = dot4(wA[j].w, hh.w, di);
            }
            {
                uint2 hh = ht2[0];
                di = dot4(wAt.x, hh.x, di); di = dot4(wAt.y, hh.y, di);
            }
            float p = x + (float)di * invsc;
            float av;
            if (q == 2) {
                float e = __expf(-2.f * p);          // tanh(g)
                av = 2.f / (1.f + e) - 1.f;
            } else {
                av = 1.f / (1.f + __expf(-p));       // sigmoid (i,f,o)
            }
            a_lds[tid] = av;
        }
        __syncthreads();
        if (tid < HD_) {
            float ig = a_lds[tid];
            float fg = a_lds[200 + tid];
            float gg = a_lds[400 + tid];
            float og = a_lds[600 + tid];
            c = fg * c + ig * gg;
            float ec = __expf(-2.f * c);
            float hn = og * (2.f / (1.f + ec) - 1.f);
            ((signed char*)hbuf)[tid] = (signed char)(int)rintf(hn * 127.f);
            lstm16[((long)(b * L_ + t)) * H_ + dir * HD_ + tid] = f32_to_bf16(hn);
        }
        x = x_n;
        __syncthreads();
    }
}

// ---------------- features via MFMA (unchanged)
__global__ __launch_bounds__(256) void feat_kernel(const unsigned short* __restrict__ lstm16,
                                                   const unsigned short* __restrict__ wtagB,
                                                   const float* __restrict__ btag,
                                                   float* __restrict__ feats) {
    __shared__ unsigned short As[128 * 40];
    __shared__ unsigned short Bs[64 * 40];
    int tid = threadIdx.x;
    int bm = blockIdx.x * 128;
    int srow = tid >> 1, half = tid & 1;
    int lane = tid & 63, wave = tid >> 6, r16 = lane & 15, kh = lane >> 4;

    f32x4 acc[2][4];
#pragma unroll
    for (int mi = 0; mi < 2; ++mi)
#pragma unroll
        for (int ni = 0; ni < 4; ++ni) acc[mi][ni] = (f32x4){0.f, 0.f, 0.f, 0.f};

    const unsigned short* Ar = lstm16 + (long)(bm + srow) * 400;
    const unsigned short* Br = wtagB + (long)srow * 400;

    for (int k0 = 0; k0 < 400; k0 += 32) {
#pragma unroll
        for (int j = 0; j < 2; ++j) {
            int off = half * 16 + j * 8;
            bool kv = (k0 + off + 8 <= 400);
            uint4 z = make_uint4(0u, 0u, 0u, 0u);
            *(uint4*)&As[srow * 40 + off] = kv ? *(const uint4*)(Ar + k0 + off) : z;
            if (srow < 64)
                *(uint4*)&Bs[srow * 40 + off] = kv ? *(const uint4*)(Br + k0 + off) : z;
        }
        __syncthreads();
        short8 af[2], bfv[4];
#pragma unroll
        for (int mi = 0; mi < 2; ++mi)
            af[mi] = *(const short8*)&As[(wave * 32 + mi * 16 + r16) * 40 + kh * 8];
#pragma unroll
        for (int ni = 0; ni < 4; ++ni)
            bfv[ni] = *(const short8*)&Bs[(ni * 16 + r16) * 40 + kh * 8];
#pragma unroll
        for (int mi = 0; mi < 2; ++mi)
#pragma unroll
            for (int ni = 0; ni < 4; ++ni)
                acc[mi][ni] = __builtin_amdgcn_mfma_f32_16x16x32_bf16(af[mi], bfv[ni], acc[mi][ni], 0, 0, 0);
        __syncthreads();
    }
#pragma unroll
    for (int ni = 0; ni < 4; ++ni) {
        int g = ni * 16 + r16;
        if (g < S_) {
            float bias = btag[g];
#pragma unroll
            for (int mi = 0; mi < 2; ++mi) {
#pragma unroll
                for (int r = 0; r < 4; ++r) {
                    int row = bm + wave * 32 + mi * 16 + kh * 4 + r;
                    feats[(long)row * S_ + g] = acc[mi][ni][r] + bias;
                }
            }
        }
    }
}

// ---------------- CRF: one wave per batch, exp-factorized + fb software pipeline.
// (R19's factorization cut crf ~113 -> ~55-60; remaining cost is plausibly the serial
// per-step 50-f32 global row read at 1 wave/block — prefetch next row during compute.)
__global__ __launch_bounds__(64) void crf_kernel(const float* __restrict__ feats,
                                                 const float* __restrict__ trans,
                                                 const int* __restrict__ tags,
                                                 const int* __restrict__ seqlens,
                                                 float* __restrict__ part) {
    __shared__ float Tt[S_ * 53];   // Tt[j*53+i] = trans[i*50+j] = T[i][j]
    __shared__ int tg[L_];
    int lane = threadIdx.x;
    int b = blockIdx.x;
    for (int idx = lane; idx < S_ * S_; idx += 64) {
        int j = idx / S_, i = idx % S_;
        Tt[j * 53 + i] = trans[i * S_ + j];
    }
    for (int idx = lane; idx < L_; idx += 64) tg[idx] = tags[b * L_ + idx];
    int slen = seqlens[b];
    const float* fb = feats + (long)b * L_ * S_;
    __syncthreads();

    bool act = lane < S_;
    const float* Trow = Tt + (act ? lane : 0) * 53;
    // preload exp(T[i][lane]) into 50 registers
    float eT[S_];
#pragma unroll
    for (int i = 0; i < S_; ++i) eT[i] = __expf(Trow[i]);

    float alpha = act ? (Trow[START_] + fb[lane]) : -1e30f;
    float lal = alpha;   // valid if slen==1
    float fval = act ? fb[S_ + lane] : 0.f;   // prefetched row t=1

    for (int t = 1; t < L_; ++t) {
        // prefetch next step's feature row (hides L2 latency under this step's compute)
        float fval_n = (act && t + 1 < L_) ? fb[(t + 1) * S_ + lane] : 0.f;
        // wave-wide max of alpha
        float m = alpha;
        for (int off = 32; off; off >>= 1) m = fmaxf(m, __shfl_xor(m, off));
        float p = __expf(alpha - m);       // inactive lanes: exp(-1e30-m)=0
        float s0 = 0.f, s1 = 0.f, s2 = 0.f, s3 = 0.f, s4 = 0.f;
#pragma unroll
        for (int i = 0; i < S_; i += 5) {
            s0 = fmaf(rlanef(p, i),     eT[i],     s0);
            s1 = fmaf(rlanef(p, i + 1), eT[i + 1], s1);
            s2 = fmaf(rlanef(p, i + 2), eT[i + 2], s2);
            s3 = fmaf(rlanef(p, i + 3), eT[i + 3], s3);
            s4 = fmaf(rlanef(p, i + 4), eT[i + 4], s4);
        }
        float s = fmaxf(((s0 + s1) + (s2 + s3)) + s4, 1e-38f);
        float anew = m + __logf(s) + fval;
        alpha = act ? anew : -1e30f;
        if (t == slen - 1) lal = alpha;
        fval = fval_n;
    }

    // unlabeled: LSE over j of (lal + T[j][END]);  T[j][END_] = Tt[END_*53 + j]
    float la = act ? (lal + Tt[END_ * 53 + lane]) : -1e30f;
    float m = la;
    for (int off = 32; off; off >>= 1) m = fmaxf(m, __shfl_xor(m, off));
    float e = act ? __expf(la - m) : 0.f;
    for (int off = 32; off; off >>= 1) e += __shfl_xor(e, off);
    float unl = m + __logf(e);

    // labeled path:  T[i][j] = Tt[j*53+i]
    float lab = 0.f;
    for (int tt = lane; tt < L_; tt += 64) {
        if (tt == 0) {
            lab += Tt[tg[0] * 53 + START_] + fb[tg[0]];
        } else if (tt < slen) {
            lab += Tt[tg[tt] * 53 + tg[tt - 1]] + fb[tt * S_ + tg[tt]];
        }
    }
    if (lane == 0) lab += Tt[END_ * 53 + tg[slen - 1]];
    for (int off = 32; off; off >>= 1) lab += __shfl_xor(lab, off);
    if (lane == 0) part[b] = unl - lab;
}

// ---------------- final: deterministic fixed-order sum of 64 partials
__global__ void fin_kernel(const float* __restrict__ part, float* __restrict__ out) {
    float s = 0.f;
    for (int i = 0; i < B_; ++i) s += part[i];
    out[0] = s;
}

extern "C" void kernel_launch(void* const* d_in, const int* in_sizes, int n_in,
                              void* d_out, int out_size, void* d_ws, size_t ws_size,
                              hipStream_t stream) {
    const int*   words = (const int*)d_in[0];
    const int*   slens = (const int*)d_in[1];
    // d_in[2] = masks: semantically (t < seq_len); not read.
    const int*   tags  = (const int*)d_in[3];
    const float* emb   = (const float*)d_in[4];
    const float* wihf  = (const float*)d_in[5];
    const float* whhf  = (const float*)d_in[6];
    const float* bf    = (const float*)d_in[7];
    const float* wihb  = (const float*)d_in[8];
    const float* whhb  = (const float*)d_in[9];
    const float* bb    = (const float*)d_in[10];
    const float* wtag  = (const float*)d_in[11];
    const float* btag  = (const float*)d_in[12];
    const float* trans = (const float*)d_in[13];

    char* ws = (char*)d_ws;
    unsigned short* xg     = (unsigned short*)(ws + OFF_XG);
    unsigned short* lstm16 = (unsigned short*)(ws + OFF_LSTM);
    unsigned short* Abf    = (unsigned short*)(ws + OFF_ABF);  // prep -> xg (overlaid by lstm16)
    unsigned short* Bbf    = (unsigned short*)(ws + OFF_BBF);  // prep -> xg (overlaid by lstm16)
    signed char*    w8     = (signed char*)(ws + OFF_SH);      // quant -> lstm
    float*          fts    = (float*)(ws + OFF_SH);            // feat -> crf (time-shared with w8)
    float*          invs   = (float*)(ws + OFF_INV);
    unsigned short* wtagB  = (unsigned short*)(ws + OFF_WTB);
    float*          biaC   = (float*)(ws + OFF_BIA);
    float*          part   = (float*)(ws + OFF_PART);
    float*          out    = (float*)d_out;

    prep_kernel<<<PREP_BLOCKS, 256, 0, stream>>>(words, emb, wihf, wihb, bf, bb,
                                                 wtag, Abf, Bbf, wtagB, biaC);
    quant_kernel<<<400, 256, 0, stream>>>(whhf, whhb, w8, invs);
    xg_gemm<<<dim3(13, 64), 256, 0, stream>>>(Abf, Bbf, biaC, xg);
    lstm_rec<<<128, 832, 0, stream>>>(xg, w8, invs, lstm16);
    feat_kernel<<<64, 256, 0, stream>>>(lstm16, wtagB, btag, fts);
    crf_kernel<<<64, 64, 0, stream>>>(fts, trans, tags, slens, part);
    fin_kernel<<<1, 1, 0, stream>>>(part, out);
}